// Round 4
// baseline (539.929 us; speedup 1.0000x reference)
//
#include <hip/hip_runtime.h>
#include <hip/hip_bf16.h>

#define N_NODES 50000
#define N_PAD   50048      // 64-row multiple for guard-free GEMM tiles
#define N_EDGES 800000
#define DF 128

// LDS row stride (ushorts): 128 bf16 + 8 pad (272 B = 17*16 B)
#define HS 136

typedef __bf16 bf16x8 __attribute__((ext_vector_type(8)));
typedef float f32x4 __attribute__((ext_vector_type(4)));
typedef unsigned int uint4v __attribute__((ext_vector_type(4)));
typedef unsigned short us4 __attribute__((ext_vector_type(4)));
typedef unsigned short us8 __attribute__((ext_vector_type(8)));

__device__ __forceinline__ unsigned short f2bf(float f) {
  unsigned u = __builtin_bit_cast(unsigned, f);
  u += 0x7FFFu + ((u >> 16) & 1u);   // RNE
  return (unsigned short)(u >> 16);
}
__device__ __forceinline__ float bf2f(unsigned short u) {
  return __builtin_bit_cast(float, ((unsigned)u) << 16);
}

// ---------------- weight prep ----------------

// Pack fp32 row-major W[128][128] (optionally W - Wsub) into bf16 MFMA
// B-fragment order.
__global__ void pack_w(const float* __restrict__ W,
                       const float* __restrict__ Wsub,
                       unsigned short* __restrict__ out) {
  const int idx = blockIdx.x * blockDim.x + threadIdx.x;   // < 2048
  const int l = idx & 63;
  const int blk = idx >> 6;
  const int ct = blk >> 2;
  const int kc = blk & 3;
  const int col = ct * 16 + (l & 15);
  const int k0 = kc * 32 + (l >> 4) * 8;
  unsigned short tmp[8];
#pragma unroll
  for (int j = 0; j < 8; ++j) {
    float v = W[(size_t)(k0 + j) * DF + col];
    if (Wsub) v -= Wsub[(size_t)(k0 + j) * DF + col];
    tmp[j] = f2bf(v);
  }
  us4 lo = { tmp[0], tmp[1], tmp[2], tmp[3] };
  us4 hi = { tmp[4], tmp[5], tmp[6], tmp[7] };
  us4* o = (us4*)(out + (size_t)idx * 8);
  o[0] = lo;
  o[1] = hi;
}

// Combined weights for eliminating feat1:
//   W20A[r][c] = sum_k W2_0[r][k] * Wa2[k][c],  Wa2 = W1_1(top) - W1_1(bot)
//   W20B[r][c] = sum_k W2_0[r][k] * Wb2[k][c],  Wb2 = W1_1(bot)
//   vA[c] = sum_k b2_0[k]*Wa2[k][c],  vB[c] = sum_k b2_0[k]*Wb2[k][c]
// grid 129 blocks x 256: b<128 -> row b of both matrices; b==128 -> vA/vB.
__global__ void wcomb_kernel(const float* __restrict__ W2_0,
                             const float* __restrict__ W1_1,
                             const float* __restrict__ b2_0,
                             float* __restrict__ W20A,
                             float* __restrict__ W20B,
                             float* __restrict__ vA,
                             float* __restrict__ vB) {
  const int b = blockIdx.x;
  const int t = threadIdx.x;
  const int c = t & 127;
  const bool isB = t >= 128;
  float acc = 0.f;
  if (b < 128) {
    const float* wrow = W2_0 + (size_t)b * DF;
    for (int k = 0; k < 128; ++k) {
      float bot = W1_1[(size_t)(128 + k) * DF + c];
      float w = isB ? bot : (W1_1[(size_t)k * DF + c] - bot);
      acc += wrow[k] * w;
    }
    if (isB) W20B[(size_t)b * DF + c] = acc;
    else     W20A[(size_t)b * DF + c] = acc;
  } else {
    for (int k = 0; k < 128; ++k) {
      float bot = W1_1[(size_t)(128 + k) * DF + c];
      float w = isB ? bot : (W1_1[(size_t)k * DF + c] - bot);
      acc += b2_0[k] * w;
    }
    if (isB) vB[c] = acc;
    else     vA[c] = acc;
  }
}

// ---------------- CSR build ----------------

__global__ void deg_kernel(const int* __restrict__ dst, int* __restrict__ deg) {
  const int e = blockIdx.x * 256 + threadIdx.x;
  if (e < N_EDGES) atomicAdd(&deg[dst[e]], 1);
}

#define SCAN_T 1024
#define SCAN_CHUNK ((N_PAD + SCAN_T - 1) / SCAN_T)
__global__ __launch_bounds__(SCAN_T)
void scan_kernel(const int* __restrict__ deg,
                 int* __restrict__ row_ptr,
                 int* __restrict__ cursor) {
  __shared__ int part[SCAN_T];
  const int t = threadIdx.x;
  const int lo = t * SCAN_CHUNK;
  const int hi = min(lo + SCAN_CHUNK, N_PAD);
  int s = 0;
  for (int i = lo; i < hi; ++i) s += deg[i];
  part[t] = s;
  __syncthreads();
  for (int off = 1; off < SCAN_T; off <<= 1) {
    int v = (t >= off) ? part[t - off] : 0;
    __syncthreads();
    part[t] += v;
    __syncthreads();
  }
  int run = (t > 0) ? part[t - 1] : 0;
  for (int i = lo; i < hi; ++i) {
    row_ptr[i] = run;
    cursor[i] = run;
    run += deg[i];
  }
  if (t == SCAN_T - 1) row_ptr[N_PAD] = part[SCAN_T - 1];
}

// Scatter edges into dst-sorted (CSR) order; keep src and original edge id.
__global__ void sort_kernel(const int* __restrict__ src,
                            const int* __restrict__ dst,
                            int* __restrict__ cursor,
                            int* __restrict__ sorted_src,
                            int* __restrict__ sorted_dst,
                            int* __restrict__ sorted_eid) {
  const int e = blockIdx.x * 256 + threadIdx.x;
  const int d = dst[e];
  const int pos = atomicAdd(&cursor[d], 1);
  sorted_src[pos] = src[e];
  sorted_dst[pos] = d;
  sorted_eid[pos] = e;
}

// ---------------- layer-1 aggregation ----------------

// Hsum1[n] = sum_{e in CSR(n)} relu(A[n] + B[src[e]]); 16 lanes/node.
__global__ __launch_bounds__(256)
void aggregate(const unsigned short* __restrict__ A,
               const unsigned short* __restrict__ B,
               const int* __restrict__ row_ptr,
               const int* __restrict__ sorted_src,
               unsigned short* __restrict__ Hsum) {
  const int t = threadIdx.x;
  const int n = blockIdx.x * 16 + (t >> 4);
  const int lane = t & 15;
  const int beg = row_ptr[n];
  const int end = row_ptr[n + 1];
  us8 av = *(const us8*)(A + (size_t)n * DF + lane * 8);
  float af[8];
#pragma unroll
  for (int j = 0; j < 8; ++j) af[j] = bf2f(av[j]);
  float acc[8] = {};
  for (int k = beg; k < end; ++k) {
    const int s = sorted_src[k];
    us8 bv = *(const us8*)(B + (size_t)s * DF + lane * 8);
#pragma unroll
    for (int j = 0; j < 8; ++j) {
      float v = af[j] + bf2f(bv[j]);
      acc[j] += v > 0.f ? v : 0.f;
    }
  }
  us8 o;
#pragma unroll
  for (int j = 0; j < 8; ++j) o[j] = f2bf(acc[j]);
  *(us8*)(Hsum + (size_t)n * DF + lane * 8) = o;
}

// ---------------- node GEMMs ----------------

// Dual-output node GEMM: stage input once, compute
//   outA = in@WA + bcA[col] + deg[row]*bdA[col]
//   outB = in@WB + bcB[col] + deg[row]*bdB[col]     (null bias ptr -> 0)
template<bool IN_BF16>
__global__ __launch_bounds__(256)
void dual_gemm(const void* __restrict__ in,
               const unsigned short* __restrict__ wpA,
               const unsigned short* __restrict__ wpB,
               const float* __restrict__ bcA, const float* __restrict__ bdA,
               const float* __restrict__ bcB, const float* __restrict__ bdB,
               const int* __restrict__ deg,
               unsigned short* __restrict__ outA,
               unsigned short* __restrict__ outB,
               int nrows_in) {
  __shared__ unsigned short xs[64 * HS];
  const int t = threadIdx.x;
  const int r0 = blockIdx.x * 64;

  {
    const int e = t >> 2, q = t & 3;
    const int grow = r0 + e;
    if (IN_BF16) {
      const us8* src = (const us8*)((const unsigned short*)in + (size_t)grow * DF + q * 32);
#pragma unroll
      for (int i = 0; i < 4; ++i) {
        us8 v = {};
        if (grow < nrows_in) v = src[i];
        *(us8*)&xs[e * HS + q * 32 + i * 8] = v;
      }
    } else {
      const float4* src = (const float4*)((const float*)in + (size_t)grow * DF) + q * 8;
#pragma unroll
      for (int i = 0; i < 8; ++i) {
        float4 v = { 0.f, 0.f, 0.f, 0.f };
        if (grow < nrows_in) v = src[i];
        us4 p = { f2bf(v.x), f2bf(v.y), f2bf(v.z), f2bf(v.w) };
        *(us4*)&xs[e * HS + q * 32 + i * 4] = p;
      }
    }
  }
  __syncthreads();

  const int w = t >> 6, l = t & 63, l15 = l & 15, lg = l >> 4;
  f32x4 accA[4][2] = {};
  f32x4 accB[4][2] = {};
  const uint4v* wvA = (const uint4v*)wpA;
  const uint4v* wvB = (const uint4v*)wpB;
#pragma unroll
  for (int kc = 0; kc < 4; ++kc) {
    bf16x8 afr[4];
#pragma unroll
    for (int rt = 0; rt < 4; ++rt)
      afr[rt] = __builtin_bit_cast(bf16x8,
          *(const uint4v*)&xs[(rt * 16 + l15) * HS + kc * 32 + lg * 8]);
#pragma unroll
    for (int c = 0; c < 2; ++c) {
      bf16x8 bfrA = __builtin_bit_cast(bf16x8, wvA[((w * 2 + c) * 4 + kc) * 64 + l]);
      bf16x8 bfrB = __builtin_bit_cast(bf16x8, wvB[((w * 2 + c) * 4 + kc) * 64 + l]);
#pragma unroll
      for (int rt = 0; rt < 4; ++rt) {
        accA[rt][c] = __builtin_amdgcn_mfma_f32_16x16x32_bf16(afr[rt], bfrA, accA[rt][c], 0, 0, 0);
        accB[rt][c] = __builtin_amdgcn_mfma_f32_16x16x32_bf16(afr[rt], bfrB, accB[rt][c], 0, 0, 0);
      }
    }
  }

#pragma unroll
  for (int c = 0; c < 2; ++c) {
    const int col = w * 32 + c * 16 + l15;
    const float cA = bcA ? bcA[col] : 0.f;
    const float dA = bdA ? bdA[col] : 0.f;
    const float cB = bcB ? bcB[col] : 0.f;
    const float dB = bdB ? bdB[col] : 0.f;
#pragma unroll
    for (int rt = 0; rt < 4; ++rt) {
#pragma unroll
      for (int r = 0; r < 4; ++r) {
        const int grow = r0 + rt * 16 + lg * 4 + r;
        const float dg = (float)deg[grow];
        outA[(size_t)grow * DF + col] = f2bf(accA[rt][c][r] + cA + dg * dA);
        outB[(size_t)grow * DF + col] = f2bf(accB[rt][c][r] + cB + dg * dB);
      }
    }
  }
}

// Single node GEMM: out(fp32) = in(fp32)@W + deg[row]*bd[col]
__global__ __launch_bounds__(256)
void node_gemm_f32(const float* __restrict__ in,
                   const unsigned short* __restrict__ wp,
                   const float* __restrict__ bd,
                   const int* __restrict__ deg,
                   float* __restrict__ out,
                   int nrows_out) {
  __shared__ unsigned short xs[64 * HS];
  const int t = threadIdx.x;
  const int r0 = blockIdx.x * 64;
  {
    const int e = t >> 2, q = t & 3;
    const int grow = r0 + e;
    const float4* src = (const float4*)(in + (size_t)grow * DF) + q * 8;
#pragma unroll
    for (int i = 0; i < 8; ++i) {
      float4 v = src[i];
      us4 p = { f2bf(v.x), f2bf(v.y), f2bf(v.z), f2bf(v.w) };
      *(us4*)&xs[e * HS + q * 32 + i * 4] = p;
    }
  }
  __syncthreads();

  const int w = t >> 6, l = t & 63, l15 = l & 15, lg = l >> 4;
  f32x4 acc[4][2] = {};
  const uint4v* wv = (const uint4v*)wp;
#pragma unroll
  for (int kc = 0; kc < 4; ++kc) {
    bf16x8 afr[4];
#pragma unroll
    for (int rt = 0; rt < 4; ++rt)
      afr[rt] = __builtin_bit_cast(bf16x8,
          *(const uint4v*)&xs[(rt * 16 + l15) * HS + kc * 32 + lg * 8]);
#pragma unroll
    for (int c = 0; c < 2; ++c) {
      bf16x8 bfr = __builtin_bit_cast(bf16x8, wv[((w * 2 + c) * 4 + kc) * 64 + l]);
#pragma unroll
      for (int rt = 0; rt < 4; ++rt)
        acc[rt][c] = __builtin_amdgcn_mfma_f32_16x16x32_bf16(afr[rt], bfr, acc[rt][c], 0, 0, 0);
    }
  }

#pragma unroll
  for (int c = 0; c < 2; ++c) {
    const int col = w * 32 + c * 16 + l15;
    const float bv = bd[col];
#pragma unroll
    for (int rt = 0; rt < 4; ++rt) {
#pragma unroll
      for (int r = 0; r < 4; ++r) {
        const int grow = r0 + rt * 16 + lg * 4 + r;
        if (grow < nrows_out)
          out[(size_t)grow * DF + col] = acc[rt][c][r] + (float)deg[grow] * bv;
      }
    }
  }
}

// ---------------- fused layer-2 edge kernel ----------------
// Processes 64 CSR-ordered edges: h = relu(A2[dst]+B2[src]) (LDS, bf16);
// msg[orig_eid] = h@W21 + b2_1;  Hsum2[n] += column-sums per dst run
// (plain store for block-interior nodes, fp32 atomic for boundary nodes).
__global__ __launch_bounds__(256)
void edge_msg_fused(const unsigned short* __restrict__ A,
                    const unsigned short* __restrict__ B,
                    const int* __restrict__ sorted_src,
                    const int* __restrict__ sorted_dst,
                    const int* __restrict__ sorted_eid,
                    const unsigned short* __restrict__ w2p,
                    const float* __restrict__ b2,
                    float* __restrict__ msg_out,
                    float* __restrict__ Hsum2) {
  __shared__ unsigned short h_s[64 * HS];
  __shared__ int node_s[64];
  __shared__ int eid_s[64];
  const int t = threadIdx.x;
  const int e0 = blockIdx.x * 64;

  // stage h
  {
    const int e = t >> 2, q = t & 3;
    const int pos = e0 + e;
    const int si = sorted_src[pos];
    const int di = sorted_dst[pos];
    if (q == 0) {
      node_s[e] = di;
      eid_s[e] = sorted_eid[pos];
    }
    const us8* ap = (const us8*)(A + (size_t)di * DF + q * 32);
    const us8* bp = (const us8*)(B + (size_t)si * DF + q * 32);
#pragma unroll
    for (int i = 0; i < 4; ++i) {
      us8 av = ap[i];
      us8 bv = bp[i];
      us8 h;
#pragma unroll
      for (int j = 0; j < 8; ++j) {
        float v = bf2f(av[j]) + bf2f(bv[j]);
        v = v > 0.f ? v : 0.f;
        h[j] = f2bf(v);
      }
      *(us8*)&h_s[e * HS + q * 32 + i * 8] = h;
    }
  }
  __syncthreads();

  const int w = t >> 6, l = t & 63, l15 = l & 15, lg = l >> 4;
  f32x4 acc[4][2] = {};
  const uint4v* wv = (const uint4v*)w2p;
#pragma unroll
  for (int kc = 0; kc < 4; ++kc) {
    bf16x8 afr[4];
#pragma unroll
    for (int rt = 0; rt < 4; ++rt)
      afr[rt] = __builtin_bit_cast(bf16x8,
          *(const uint4v*)&h_s[(rt * 16 + l15) * HS + kc * 32 + lg * 8]);
#pragma unroll
    for (int c = 0; c < 2; ++c) {
      bf16x8 bfr = __builtin_bit_cast(bf16x8, wv[((w * 2 + c) * 4 + kc) * 64 + l]);
#pragma unroll
      for (int rt = 0; rt < 4; ++rt)
        acc[rt][c] = __builtin_amdgcn_mfma_f32_16x16x32_bf16(afr[rt], bfr, acc[rt][c], 0, 0, 0);
    }
  }

  // msg epilogue (original edge order via eid)
#pragma unroll
  for (int c = 0; c < 2; ++c) {
    const int col = w * 32 + c * 16 + l15;
    const float bv = b2[col];
#pragma unroll
    for (int rt = 0; rt < 4; ++rt) {
#pragma unroll
      for (int r = 0; r < 4; ++r) {
        const int row = rt * 16 + lg * 4 + r;
        msg_out[(size_t)eid_s[row] * DF + col] = acc[rt][c][r] + bv;
      }
    }
  }

  // segmented column-sum -> Hsum2 (threads 0..127, one column each)
  if (t < 128) {
    const int col = t;
    const int prev = (e0 > 0) ? sorted_dst[e0 - 1] : -1;
    const int next = (e0 + 64 < N_EDGES) ? sorted_dst[e0 + 64] : -1;
    int run_n = node_s[0];
    int run_a = 0;
    float racc = 0.f;
    for (int r = 0; r < 64; ++r) {
      const int n = node_s[r];
      if (n != run_n) {
        float* p = &Hsum2[(size_t)run_n * DF + col];
        if (run_a == 0 && prev == run_n) unsafeAtomicAdd(p, racc);
        else *p = racc;
        run_n = n; run_a = r; racc = 0.f;
      }
      racc += bf2f(h_s[r * HS + col]);
    }
    float* p = &Hsum2[(size_t)run_n * DF + col];
    if ((run_a == 0 && prev == run_n) || next == run_n) unsafeAtomicAdd(p, racc);
    else *p = racc;
  }
}

extern "C" void kernel_launch(void* const* d_in, const int* in_sizes, int n_in,
                              void* d_out, int out_size, void* d_ws, size_t ws_size,
                              hipStream_t stream) {
  const float* x    = (const float*)d_in[0];
  const int*   eidx = (const int*)d_in[1];
  const float* W1_0 = (const float*)d_in[2];
  const float* b1_0 = (const float*)d_in[3];
  const float* W2_0 = (const float*)d_in[4];
  const float* b2_0 = (const float*)d_in[5];
  const float* W1_1 = (const float*)d_in[6];
  const float* b1_1 = (const float*)d_in[7];
  const float* W2_1 = (const float*)d_in[8];
  const float* b2_1 = (const float*)d_in[9];

  const int* src = eidx;
  const int* dst = eidx + N_EDGES;

  float* feat2 = (float*)d_out;
  float* msg2  = feat2 + (size_t)N_NODES * DF;

  // ---- workspace layout ----
  char* ws = (char*)d_ws;
  const size_t BF_ROWS = (size_t)N_PAD * DF;
  unsigned short* A     = (unsigned short*)ws;  ws += BF_ROWS * 2;      // 12.8 MB
  unsigned short* Bm    = (unsigned short*)ws;  ws += BF_ROWS * 2;      // 12.8 MB
  unsigned short* Hsum1 = (unsigned short*)ws;  ws += BF_ROWS * 2;      // 12.8 MB
  float*          Hsum2 = (float*)ws;           ws += BF_ROWS * 4;      // 25.6 MB
  int* deg        = (int*)ws;  ws += (size_t)N_PAD * 4;
  int* row_ptr    = (int*)ws;  ws += (size_t)(N_PAD + 1) * 4;
  int* cursor     = (int*)ws;  ws += (size_t)N_PAD * 4;
  int* sorted_src = (int*)ws;  ws += (size_t)N_EDGES * 4;               // 3.2 MB
  int* sorted_dst = (int*)ws;  ws += (size_t)N_EDGES * 4;               // 3.2 MB
  int* sorted_eid = (int*)ws;  ws += (size_t)N_EDGES * 4;               // 3.2 MB
  float* W20A_f = (float*)ws;  ws += 16384 * 4;
  float* W20B_f = (float*)ws;  ws += 16384 * 4;
  float* vA     = (float*)ws;  ws += 128 * 4;
  float* vB     = (float*)ws;  ws += 128 * 4;
  unsigned short* wa1p  = (unsigned short*)ws;  ws += 16384 * 2;
  unsigned short* wb1p  = (unsigned short*)ws;  ws += 16384 * 2;
  unsigned short* w20Ap = (unsigned short*)ws;  ws += 16384 * 2;
  unsigned short* w20Bp = (unsigned short*)ws;  ws += 16384 * 2;
  unsigned short* w21p  = (unsigned short*)ws;  ws += 16384 * 2;

  hipMemsetAsync(deg, 0, (size_t)N_PAD * 4, stream);
  hipMemsetAsync(Hsum2, 0, BF_ROWS * 4, stream);

  // Weight prep.  W1 rows 0..127 multiply x_i, rows 128..255 multiply (x_j-x_i):
  // Wa = top - bot (applies to x_i = x[dst]), Wb = bot (applies to x_j = x[src]).
  pack_w<<<8, 256, 0, stream>>>(W1_0, W1_0 + 128 * DF, wa1p);
  pack_w<<<8, 256, 0, stream>>>(W1_0 + 128 * DF, nullptr, wb1p);
  pack_w<<<8, 256, 0, stream>>>(W2_1, nullptr, w21p);
  wcomb_kernel<<<129, 256, 0, stream>>>(W2_0, W1_1, b2_0, W20A_f, W20B_f, vA, vB);
  pack_w<<<8, 256, 0, stream>>>(W20A_f, nullptr, w20Ap);
  pack_w<<<8, 256, 0, stream>>>(W20B_f, nullptr, w20Bp);

  // CSR build
  deg_kernel<<<N_EDGES / 256, 256, 0, stream>>>(dst, deg);
  scan_kernel<<<1, SCAN_T, 0, stream>>>(deg, row_ptr, cursor);
  sort_kernel<<<N_EDGES / 256, 256, 0, stream>>>(src, dst, cursor,
                                                 sorted_src, sorted_dst, sorted_eid);

  const int NG = N_PAD / 64;   // 782
  const int NA = N_PAD / 16;   // 3128

  // Layer 1: A1 = x@Wa1 + b1_0,  B1 = x@Wb1
  dual_gemm<false><<<NG, 256, 0, stream>>>(x, wa1p, wb1p,
                                           b1_0, nullptr, nullptr, nullptr,
                                           deg, A, Bm, N_NODES);
  aggregate<<<NA, 256, 0, stream>>>(A, Bm, row_ptr, sorted_src, Hsum1);

  // Layer 2 inputs via combined weights (feat1 eliminated):
  //   A2 = Hsum1@W20A + b1_1 + deg*vA,  B2 = Hsum1@W20B + deg*vB
  dual_gemm<true><<<NG, 256, 0, stream>>>(Hsum1, w20Ap, w20Bp,
                                          b1_1, vA, nullptr, vB,
                                          deg, A, Bm, N_PAD);

  // Fused: msg2 (orig order) + Hsum2 (CSR segmented reduction)
  edge_msg_fused<<<N_EDGES / 64, 256, 0, stream>>>(A, Bm, sorted_src, sorted_dst,
                                                   sorted_eid, w21p, b2_1,
                                                   msg2, Hsum2);

  // feat2 = Hsum2@W21 + deg*b2_1
  node_gemm_f32<<<NG, 256, 0, stream>>>(Hsum2, w21p, b2_1, deg, feat2, N_NODES);
}

// Round 5
// 519.132 us; speedup vs baseline: 1.0401x; 1.0401x over previous
//
#include <hip/hip_runtime.h>
#include <hip/hip_bf16.h>

#define N_NODES 50000
#define N_PAD   50048      // 64-row multiple for guard-free GEMM tiles
#define N_EDGES 800000
#define DF 128

// LDS row stride (ushorts): 128 bf16 + 8 pad (272 B = 17*16 B)
#define HS 136

typedef __bf16 bf16x8 __attribute__((ext_vector_type(8)));
typedef float f32x4 __attribute__((ext_vector_type(4)));
typedef unsigned int uint4v __attribute__((ext_vector_type(4)));
typedef unsigned short us4 __attribute__((ext_vector_type(4)));
typedef unsigned short us8 __attribute__((ext_vector_type(8)));

__device__ __forceinline__ unsigned short f2bf(float f) {
  unsigned u = __builtin_bit_cast(unsigned, f);
  u += 0x7FFFu + ((u >> 16) & 1u);   // RNE
  return (unsigned short)(u >> 16);
}
__device__ __forceinline__ float bf2f(unsigned short u) {
  return __builtin_bit_cast(float, ((unsigned)u) << 16);
}

// ---------------- weight prep ----------------

// Pack fp32 row-major W[128][128] (optionally W - Wsub) into bf16 MFMA
// B-fragment order.
__global__ void pack_w(const float* __restrict__ W,
                       const float* __restrict__ Wsub,
                       unsigned short* __restrict__ out) {
  const int idx = blockIdx.x * blockDim.x + threadIdx.x;   // < 2048
  const int l = idx & 63;
  const int blk = idx >> 6;
  const int ct = blk >> 2;
  const int kc = blk & 3;
  const int col = ct * 16 + (l & 15);
  const int k0 = kc * 32 + (l >> 4) * 8;
  unsigned short tmp[8];
#pragma unroll
  for (int j = 0; j < 8; ++j) {
    float v = W[(size_t)(k0 + j) * DF + col];
    if (Wsub) v -= Wsub[(size_t)(k0 + j) * DF + col];
    tmp[j] = f2bf(v);
  }
  us4 lo = { tmp[0], tmp[1], tmp[2], tmp[3] };
  us4 hi = { tmp[4], tmp[5], tmp[6], tmp[7] };
  us4* o = (us4*)(out + (size_t)idx * 8);
  o[0] = lo;
  o[1] = hi;
}

// Combined weights eliminating feat1:
//   W20A = W2_0 @ (W1_1_top - W1_1_bot), W20B = W2_0 @ W1_1_bot
//   vA = b2_0 @ (W1_1_top - W1_1_bot),   vB = b2_0 @ W1_1_bot
__global__ void wcomb_kernel(const float* __restrict__ W2_0,
                             const float* __restrict__ W1_1,
                             const float* __restrict__ b2_0,
                             float* __restrict__ W20A,
                             float* __restrict__ W20B,
                             float* __restrict__ vA,
                             float* __restrict__ vB) {
  const int b = blockIdx.x;
  const int t = threadIdx.x;
  const int c = t & 127;
  const bool isB = t >= 128;
  float acc = 0.f;
  if (b < 128) {
    const float* wrow = W2_0 + (size_t)b * DF;
    for (int k = 0; k < 128; ++k) {
      float bot = W1_1[(size_t)(128 + k) * DF + c];
      float w = isB ? bot : (W1_1[(size_t)k * DF + c] - bot);
      acc += wrow[k] * w;
    }
    if (isB) W20B[(size_t)b * DF + c] = acc;
    else     W20A[(size_t)b * DF + c] = acc;
  } else {
    for (int k = 0; k < 128; ++k) {
      float bot = W1_1[(size_t)(128 + k) * DF + c];
      float w = isB ? bot : (W1_1[(size_t)k * DF + c] - bot);
      acc += b2_0[k] * w;
    }
    if (isB) vB[c] = acc;
    else     vA[c] = acc;
  }
}

// ---------------- CSR build ----------------

__global__ void deg_kernel(const int* __restrict__ dst, int* __restrict__ deg) {
  const int e = blockIdx.x * 256 + threadIdx.x;
  if (e < N_EDGES) atomicAdd(&deg[dst[e]], 1);
}

#define SCAN_T 1024
#define SCAN_CHUNK ((N_PAD + SCAN_T - 1) / SCAN_T)
__global__ __launch_bounds__(SCAN_T)
void scan_kernel(const int* __restrict__ deg,
                 int* __restrict__ row_ptr,
                 int* __restrict__ cursor) {
  __shared__ int part[SCAN_T];
  const int t = threadIdx.x;
  const int lo = t * SCAN_CHUNK;
  const int hi = min(lo + SCAN_CHUNK, N_PAD);
  int s = 0;
  for (int i = lo; i < hi; ++i) s += deg[i];
  part[t] = s;
  __syncthreads();
  for (int off = 1; off < SCAN_T; off <<= 1) {
    int v = (t >= off) ? part[t - off] : 0;
    __syncthreads();
    part[t] += v;
    __syncthreads();
  }
  int run = (t > 0) ? part[t - 1] : 0;
  for (int i = lo; i < hi; ++i) {
    row_ptr[i] = run;
    cursor[i] = run;
    run += deg[i];
  }
  if (t == SCAN_T - 1) row_ptr[N_PAD] = part[SCAN_T - 1];
}

__global__ void sort_kernel(const int* __restrict__ src,
                            const int* __restrict__ dst,
                            int* __restrict__ cursor,
                            int* __restrict__ sorted_src) {
  const int e = blockIdx.x * 256 + threadIdx.x;
  const int d = dst[e];
  const int pos = atomicAdd(&cursor[d], 1);
  sorted_src[pos] = src[e];
}

// ---------------- aggregation ----------------
// Hsum[n] = sum_{e in CSR(n)} relu(A[n] + B[src[e]]); 16 lanes/node,
// gather loop unrolled x4 for L2-latency hiding.
__global__ __launch_bounds__(256)
void aggregate(const unsigned short* __restrict__ A,
               const unsigned short* __restrict__ B,
               const int* __restrict__ row_ptr,
               const int* __restrict__ sorted_src,
               unsigned short* __restrict__ Hsum) {
  const int t = threadIdx.x;
  const int n = blockIdx.x * 16 + (t >> 4);
  const int lane = t & 15;
  const int beg = row_ptr[n];
  const int end = row_ptr[n + 1];
  us8 av = *(const us8*)(A + (size_t)n * DF + lane * 8);
  float af[8];
#pragma unroll
  for (int j = 0; j < 8; ++j) af[j] = bf2f(av[j]);
  float acc[8] = {};
  int k = beg;
  for (; k + 4 <= end; k += 4) {
    const int s0 = sorted_src[k + 0];
    const int s1 = sorted_src[k + 1];
    const int s2 = sorted_src[k + 2];
    const int s3 = sorted_src[k + 3];
    us8 b0 = *(const us8*)(B + (size_t)s0 * DF + lane * 8);
    us8 b1 = *(const us8*)(B + (size_t)s1 * DF + lane * 8);
    us8 b2 = *(const us8*)(B + (size_t)s2 * DF + lane * 8);
    us8 b3 = *(const us8*)(B + (size_t)s3 * DF + lane * 8);
#pragma unroll
    for (int j = 0; j < 8; ++j) {
      float v0 = af[j] + bf2f(b0[j]);
      float v1 = af[j] + bf2f(b1[j]);
      float v2 = af[j] + bf2f(b2[j]);
      float v3 = af[j] + bf2f(b3[j]);
      acc[j] += (v0 > 0.f ? v0 : 0.f) + (v1 > 0.f ? v1 : 0.f)
              + (v2 > 0.f ? v2 : 0.f) + (v3 > 0.f ? v3 : 0.f);
    }
  }
  for (; k < end; ++k) {
    const int s = sorted_src[k];
    us8 bv = *(const us8*)(B + (size_t)s * DF + lane * 8);
#pragma unroll
    for (int j = 0; j < 8; ++j) {
      float v = af[j] + bf2f(bv[j]);
      acc[j] += v > 0.f ? v : 0.f;
    }
  }
  us8 o;
#pragma unroll
  for (int j = 0; j < 8; ++j) o[j] = f2bf(acc[j]);
  *(us8*)(Hsum + (size_t)n * DF + lane * 8) = o;
}

// ---------------- node GEMMs ----------------

// Dual-output node GEMM: stage input once, compute
//   outA = in@WA + bcA[col] + deg[row]*bdA[col]
//   outB = in@WB + bcB[col] + deg[row]*bdB[col]     (null bias ptr -> 0)
template<bool IN_BF16>
__global__ __launch_bounds__(256)
void dual_gemm(const void* __restrict__ in,
               const unsigned short* __restrict__ wpA,
               const unsigned short* __restrict__ wpB,
               const float* __restrict__ bcA, const float* __restrict__ bdA,
               const float* __restrict__ bcB, const float* __restrict__ bdB,
               const int* __restrict__ deg,
               unsigned short* __restrict__ outA,
               unsigned short* __restrict__ outB,
               int nrows_in) {
  __shared__ unsigned short xs[64 * HS];
  const int t = threadIdx.x;
  const int r0 = blockIdx.x * 64;

  {
    const int e = t >> 2, q = t & 3;
    const int grow = r0 + e;
    if (IN_BF16) {
      const us8* src = (const us8*)((const unsigned short*)in + (size_t)grow * DF + q * 32);
#pragma unroll
      for (int i = 0; i < 4; ++i) {
        us8 v = {};
        if (grow < nrows_in) v = src[i];
        *(us8*)&xs[e * HS + q * 32 + i * 8] = v;
      }
    } else {
      const float4* src = (const float4*)((const float*)in + (size_t)grow * DF) + q * 8;
#pragma unroll
      for (int i = 0; i < 8; ++i) {
        float4 v = { 0.f, 0.f, 0.f, 0.f };
        if (grow < nrows_in) v = src[i];
        us4 p = { f2bf(v.x), f2bf(v.y), f2bf(v.z), f2bf(v.w) };
        *(us4*)&xs[e * HS + q * 32 + i * 4] = p;
      }
    }
  }
  __syncthreads();

  const int w = t >> 6, l = t & 63, l15 = l & 15, lg = l >> 4;
  f32x4 accA[4][2] = {};
  f32x4 accB[4][2] = {};
  const uint4v* wvA = (const uint4v*)wpA;
  const uint4v* wvB = (const uint4v*)wpB;
#pragma unroll
  for (int kc = 0; kc < 4; ++kc) {
    bf16x8 afr[4];
#pragma unroll
    for (int rt = 0; rt < 4; ++rt)
      afr[rt] = __builtin_bit_cast(bf16x8,
          *(const uint4v*)&xs[(rt * 16 + l15) * HS + kc * 32 + lg * 8]);
#pragma unroll
    for (int c = 0; c < 2; ++c) {
      bf16x8 bfrA = __builtin_bit_cast(bf16x8, wvA[((w * 2 + c) * 4 + kc) * 64 + l]);
      bf16x8 bfrB = __builtin_bit_cast(bf16x8, wvB[((w * 2 + c) * 4 + kc) * 64 + l]);
#pragma unroll
      for (int rt = 0; rt < 4; ++rt) {
        accA[rt][c] = __builtin_amdgcn_mfma_f32_16x16x32_bf16(afr[rt], bfrA, accA[rt][c], 0, 0, 0);
        accB[rt][c] = __builtin_amdgcn_mfma_f32_16x16x32_bf16(afr[rt], bfrB, accB[rt][c], 0, 0, 0);
      }
    }
  }

#pragma unroll
  for (int c = 0; c < 2; ++c) {
    const int col = w * 32 + c * 16 + l15;
    const float cA = bcA ? bcA[col] : 0.f;
    const float dA = bdA ? bdA[col] : 0.f;
    const float cB = bcB ? bcB[col] : 0.f;
    const float dB = bdB ? bdB[col] : 0.f;
#pragma unroll
    for (int rt = 0; rt < 4; ++rt) {
#pragma unroll
      for (int r = 0; r < 4; ++r) {
        const int grow = r0 + rt * 16 + lg * 4 + r;
        const float dg = (float)deg[grow];
        outA[(size_t)grow * DF + col] = f2bf(accA[rt][c][r] + cA + dg * dA);
        outB[(size_t)grow * DF + col] = f2bf(accB[rt][c][r] + cB + dg * dB);
      }
    }
  }
}

// Single node GEMM: BIAS_MODE: 0 none, 1 bias[col], 2 deg[row]*bias[col]
template<int BIAS_MODE, bool IN_BF16, bool OUT_F32>
__global__ __launch_bounds__(256)
void node_gemm(const void* __restrict__ in,
               const unsigned short* __restrict__ wp,
               const float* __restrict__ bias,
               const int* __restrict__ deg,
               void* __restrict__ outv,
               int nrows_in, int nrows_out) {
  __shared__ unsigned short xs[64 * HS];
  const int t = threadIdx.x;
  const int r0 = blockIdx.x * 64;

  {
    const int e = t >> 2, q = t & 3;
    const int grow = r0 + e;
    if (IN_BF16) {
      const us8* src = (const us8*)((const unsigned short*)in + (size_t)grow * DF + q * 32);
#pragma unroll
      for (int i = 0; i < 4; ++i) {
        us8 v = {};
        if (grow < nrows_in) v = src[i];
        *(us8*)&xs[e * HS + q * 32 + i * 8] = v;
      }
    } else {
      const float4* src = (const float4*)((const float*)in + (size_t)grow * DF) + q * 8;
#pragma unroll
      for (int i = 0; i < 8; ++i) {
        float4 v = { 0.f, 0.f, 0.f, 0.f };
        if (grow < nrows_in) v = src[i];
        us4 p = { f2bf(v.x), f2bf(v.y), f2bf(v.z), f2bf(v.w) };
        *(us4*)&xs[e * HS + q * 32 + i * 4] = p;
      }
    }
  }
  __syncthreads();

  const int w = t >> 6, l = t & 63, l15 = l & 15, lg = l >> 4;
  f32x4 acc[4][2] = {};
  const uint4v* wv = (const uint4v*)wp;
#pragma unroll
  for (int kc = 0; kc < 4; ++kc) {
    bf16x8 afr[4];
#pragma unroll
    for (int rt = 0; rt < 4; ++rt)
      afr[rt] = __builtin_bit_cast(bf16x8,
          *(const uint4v*)&xs[(rt * 16 + l15) * HS + kc * 32 + lg * 8]);
#pragma unroll
    for (int c = 0; c < 2; ++c) {
      bf16x8 bfr = __builtin_bit_cast(bf16x8, wv[((w * 2 + c) * 4 + kc) * 64 + l]);
#pragma unroll
      for (int rt = 0; rt < 4; ++rt)
        acc[rt][c] = __builtin_amdgcn_mfma_f32_16x16x32_bf16(afr[rt], bfr, acc[rt][c], 0, 0, 0);
    }
  }

#pragma unroll
  for (int c = 0; c < 2; ++c) {
    const int col = w * 32 + c * 16 + l15;
    const float bcol = (BIAS_MODE >= 1) ? bias[col] : 0.f;
#pragma unroll
    for (int rt = 0; rt < 4; ++rt) {
#pragma unroll
      for (int r = 0; r < 4; ++r) {
        const int grow = r0 + rt * 16 + lg * 4 + r;
        if (grow >= nrows_out) continue;
        float bv = bcol;
        if (BIAS_MODE == 2) bv = (float)deg[grow] * bcol;
        const float v = acc[rt][c][r] + bv;
        if (OUT_F32) ((float*)outv)[(size_t)grow * DF + col] = v;
        else ((unsigned short*)outv)[(size_t)grow * DF + col] = f2bf(v);
      }
    }
  }
}

// ---------------- layer-2 per-edge GEMM (original order, coalesced) ----------------
__global__ __launch_bounds__(256)
void edge_msg(const unsigned short* __restrict__ A,
              const unsigned short* __restrict__ B,
              const int* __restrict__ src,
              const int* __restrict__ dst,
              const unsigned short* __restrict__ w2p,
              const float* __restrict__ b2,
              float* __restrict__ msg_out) {
  __shared__ unsigned short h_s[64 * HS];
  const int t = threadIdx.x;
  const int e0 = blockIdx.x * 64;

  {
    const int e = t >> 2, q = t & 3;
    const int ge = e0 + e;
    const int si = src[ge];
    const int di = dst[ge];
    const us8* ap = (const us8*)(A + (size_t)di * DF + q * 32);
    const us8* bp = (const us8*)(B + (size_t)si * DF + q * 32);
    us8 av[4], bv[4];
#pragma unroll
    for (int i = 0; i < 4; ++i) { av[i] = ap[i]; bv[i] = bp[i]; }
#pragma unroll
    for (int i = 0; i < 4; ++i) {
      us8 h;
#pragma unroll
      for (int j = 0; j < 8; ++j) {
        float v = bf2f(av[i][j]) + bf2f(bv[i][j]);
        v = v > 0.f ? v : 0.f;
        h[j] = f2bf(v);
      }
      *(us8*)&h_s[e * HS + q * 32 + i * 8] = h;
    }
  }
  __syncthreads();

  const int w = t >> 6, l = t & 63, l15 = l & 15, lg = l >> 4;
  f32x4 acc[4][2] = {};
  const uint4v* wv = (const uint4v*)w2p;
#pragma unroll
  for (int kc = 0; kc < 4; ++kc) {
    bf16x8 afr[4];
#pragma unroll
    for (int rt = 0; rt < 4; ++rt)
      afr[rt] = __builtin_bit_cast(bf16x8,
          *(const uint4v*)&h_s[(rt * 16 + l15) * HS + kc * 32 + lg * 8]);
#pragma unroll
    for (int c = 0; c < 2; ++c) {
      bf16x8 bfr = __builtin_bit_cast(bf16x8, wv[((w * 2 + c) * 4 + kc) * 64 + l]);
#pragma unroll
      for (int rt = 0; rt < 4; ++rt)
        acc[rt][c] = __builtin_amdgcn_mfma_f32_16x16x32_bf16(afr[rt], bfr, acc[rt][c], 0, 0, 0);
    }
  }

#pragma unroll
  for (int c = 0; c < 2; ++c) {
    const int col = w * 32 + c * 16 + l15;
    const float bv = b2[col];
#pragma unroll
    for (int rt = 0; rt < 4; ++rt) {
#pragma unroll
      for (int r = 0; r < 4; ++r) {
        const int row = rt * 16 + lg * 4 + r;
        msg_out[(size_t)(e0 + row) * DF + col] = acc[rt][c][r] + bv;
      }
    }
  }
}

extern "C" void kernel_launch(void* const* d_in, const int* in_sizes, int n_in,
                              void* d_out, int out_size, void* d_ws, size_t ws_size,
                              hipStream_t stream) {
  const float* x    = (const float*)d_in[0];
  const int*   eidx = (const int*)d_in[1];
  const float* W1_0 = (const float*)d_in[2];
  const float* b1_0 = (const float*)d_in[3];
  const float* W2_0 = (const float*)d_in[4];
  const float* b2_0 = (const float*)d_in[5];
  const float* W1_1 = (const float*)d_in[6];
  const float* b1_1 = (const float*)d_in[7];
  const float* W2_1 = (const float*)d_in[8];
  const float* b2_1 = (const float*)d_in[9];

  const int* src = eidx;
  const int* dst = eidx + N_EDGES;

  float* feat2 = (float*)d_out;
  float* msg2  = feat2 + (size_t)N_NODES * DF;

  // ---- workspace layout ----
  char* ws = (char*)d_ws;
  const size_t BF_ROWS = (size_t)N_PAD * DF;
  unsigned short* A     = (unsigned short*)ws;  ws += BF_ROWS * 2;      // 12.8 MB
  unsigned short* Bm    = (unsigned short*)ws;  ws += BF_ROWS * 2;      // 12.8 MB
  unsigned short* Hsum1 = (unsigned short*)ws;  ws += BF_ROWS * 2;      // 12.8 MB
  unsigned short* Hsum2 = (unsigned short*)ws;  ws += BF_ROWS * 2;      // 12.8 MB
  int* deg        = (int*)ws;  ws += (size_t)N_PAD * 4;
  int* row_ptr    = (int*)ws;  ws += (size_t)(N_PAD + 1) * 4;
  int* cursor     = (int*)ws;  ws += (size_t)N_PAD * 4;
  int* sorted_src = (int*)ws;  ws += (size_t)N_EDGES * 4;               // 3.2 MB
  float* W20A_f = (float*)ws;  ws += 16384 * 4;
  float* W20B_f = (float*)ws;  ws += 16384 * 4;
  float* vA     = (float*)ws;  ws += 128 * 4;
  float* vB     = (float*)ws;  ws += 128 * 4;
  unsigned short* wa1p  = (unsigned short*)ws;  ws += 16384 * 2;
  unsigned short* wb1p  = (unsigned short*)ws;  ws += 16384 * 2;
  unsigned short* w20Ap = (unsigned short*)ws;  ws += 16384 * 2;
  unsigned short* w20Bp = (unsigned short*)ws;  ws += 16384 * 2;
  unsigned short* w21p  = (unsigned short*)ws;  ws += 16384 * 2;

  hipMemsetAsync(deg, 0, (size_t)N_PAD * 4, stream);

  // Weight prep. W1 rows 0..127 multiply x_i, rows 128..255 multiply (x_j-x_i):
  // Wa = top - bot (applies to x_i = x[dst]), Wb = bot (applies to x_j = x[src]).
  pack_w<<<8, 256, 0, stream>>>(W1_0, W1_0 + 128 * DF, wa1p);
  pack_w<<<8, 256, 0, stream>>>(W1_0 + 128 * DF, nullptr, wb1p);
  pack_w<<<8, 256, 0, stream>>>(W2_1, nullptr, w21p);
  wcomb_kernel<<<129, 256, 0, stream>>>(W2_0, W1_1, b2_0, W20A_f, W20B_f, vA, vB);
  pack_w<<<8, 256, 0, stream>>>(W20A_f, nullptr, w20Ap);
  pack_w<<<8, 256, 0, stream>>>(W20B_f, nullptr, w20Bp);

  // CSR build
  deg_kernel<<<N_EDGES / 256, 256, 0, stream>>>(dst, deg);
  scan_kernel<<<1, SCAN_T, 0, stream>>>(deg, row_ptr, cursor);
  sort_kernel<<<N_EDGES / 256, 256, 0, stream>>>(src, dst, cursor, sorted_src);

  const int NG = N_PAD / 64;   // 782
  const int NA = N_PAD / 16;   // 3128

  // Layer 1: A1 = x@Wa1 + b1_0,  B1 = x@Wb1
  dual_gemm<false><<<NG, 256, 0, stream>>>(x, wa1p, wb1p,
                                           b1_0, nullptr, nullptr, nullptr,
                                           deg, A, Bm, N_NODES);
  aggregate<<<NA, 256, 0, stream>>>(A, Bm, row_ptr, sorted_src, Hsum1);

  // Layer 2 inputs via combined weights (feat1 eliminated):
  //   A2 = Hsum1@W20A + b1_1 + deg*vA,  B2 = Hsum1@W20B + deg*vB
  dual_gemm<true><<<NG, 256, 0, stream>>>(Hsum1, w20Ap, w20Bp,
                                          b1_1, vA, nullptr, vB,
                                          deg, A, Bm, N_PAD);

  // msg2 in original edge order (coalesced write)
  edge_msg<<<N_EDGES / 64, 256, 0, stream>>>(A, Bm, src, dst, w21p, b2_1, msg2);

  // Hsum2 then feat2 = Hsum2@W21 + deg*b2_1
  aggregate<<<NA, 256, 0, stream>>>(A, Bm, row_ptr, sorted_src, Hsum2);
  node_gemm<2, true, true><<<NG, 256, 0, stream>>>(Hsum2, w21p, b2_1, deg,
                                                   feat2, N_PAD, N_NODES);
}

// Round 6
// 504.167 us; speedup vs baseline: 1.0709x; 1.0297x over previous
//
#include <hip/hip_runtime.h>
#include <hip/hip_bf16.h>

#define N_NODES 50000
#define N_PAD   50048      // 64-row multiple for guard-free GEMM tiles
#define N_EDGES 800000
#define DF 128

// LDS row stride (ushorts): 128 bf16 + 8 pad (272 B = 17*16 B)
#define HS 136

typedef __bf16 bf16x8 __attribute__((ext_vector_type(8)));
typedef float f32x4 __attribute__((ext_vector_type(4)));
typedef unsigned int uint4v __attribute__((ext_vector_type(4)));
typedef unsigned short us4 __attribute__((ext_vector_type(4)));
typedef unsigned short us8 __attribute__((ext_vector_type(8)));

__device__ __forceinline__ unsigned short f2bf(float f) {
  unsigned u = __builtin_bit_cast(unsigned, f);
  u += 0x7FFFu + ((u >> 16) & 1u);   // RNE
  return (unsigned short)(u >> 16);
}
__device__ __forceinline__ float bf2f(unsigned short u) {
  return __builtin_bit_cast(float, ((unsigned)u) << 16);
}

// ---------------- weight prep ----------------

// Combined weights eliminating feat1:
//   W20A = W2_0 @ (W1_1_top - W1_1_bot), W20B = W2_0 @ W1_1_bot
//   vA = b2_0 @ (W1_1_top - W1_1_bot),   vB = b2_0 @ W1_1_bot
__global__ void wcomb_kernel(const float* __restrict__ W2_0,
                             const float* __restrict__ W1_1,
                             const float* __restrict__ b2_0,
                             float* __restrict__ W20A,
                             float* __restrict__ W20B,
                             float* __restrict__ vA,
                             float* __restrict__ vB) {
  const int b = blockIdx.x;
  const int t = threadIdx.x;
  const int c = t & 127;
  const bool isB = t >= 128;
  float acc = 0.f;
  if (b < 128) {
    const float* wrow = W2_0 + (size_t)b * DF;
    for (int k = 0; k < 128; ++k) {
      float bot = W1_1[(size_t)(128 + k) * DF + c];
      float w = isB ? bot : (W1_1[(size_t)k * DF + c] - bot);
      acc += wrow[k] * w;
    }
    if (isB) W20B[(size_t)b * DF + c] = acc;
    else     W20A[(size_t)b * DF + c] = acc;
  } else {
    for (int k = 0; k < 128; ++k) {
      float bot = W1_1[(size_t)(128 + k) * DF + c];
      float w = isB ? bot : (W1_1[(size_t)k * DF + c] - bot);
      acc += b2_0[k] * w;
    }
    if (isB) vB[c] = acc;
    else     vA[c] = acc;
  }
}

// Pack all 5 fp32 [128][128] matrices into bf16 MFMA B-fragment order.
// grid = 40 blocks: mat = blockIdx.x>>3.
__global__ void pack_all(const float* __restrict__ W1_0,
                         const float* __restrict__ W2_1,
                         const float* __restrict__ W20A_f,
                         const float* __restrict__ W20B_f,
                         unsigned short* __restrict__ wa1p,
                         unsigned short* __restrict__ wb1p,
                         unsigned short* __restrict__ w21p,
                         unsigned short* __restrict__ w20Ap,
                         unsigned short* __restrict__ w20Bp) {
  const int mat = blockIdx.x >> 3;
  const int idx = (blockIdx.x & 7) * 256 + threadIdx.x;   // < 2048
  const int l = idx & 63;
  const int blk = idx >> 6;
  const int ct = blk >> 2;
  const int kc = blk & 3;
  const int col = ct * 16 + (l & 15);
  const int k0 = kc * 32 + (l >> 4) * 8;
  const float* W;
  const float* Wsub = nullptr;
  unsigned short* out;
  switch (mat) {
    case 0: W = W1_0;            Wsub = W1_0 + 128 * DF; out = wa1p;  break;
    case 1: W = W1_0 + 128 * DF;                         out = wb1p;  break;
    case 2: W = W2_1;                                    out = w21p;  break;
    case 3: W = W20A_f;                                  out = w20Ap; break;
    default: W = W20B_f;                                 out = w20Bp; break;
  }
  unsigned short tmp[8];
#pragma unroll
  for (int j = 0; j < 8; ++j) {
    float v = W[(size_t)(k0 + j) * DF + col];
    if (Wsub) v -= Wsub[(size_t)(k0 + j) * DF + col];
    tmp[j] = f2bf(v);
  }
  us4 lo = { tmp[0], tmp[1], tmp[2], tmp[3] };
  us4 hi = { tmp[4], tmp[5], tmp[6], tmp[7] };
  us4* o = (us4*)(out + (size_t)idx * 8);
  o[0] = lo;
  o[1] = hi;
}

// ---------------- CSR build ----------------

__global__ void deg_kernel(const int* __restrict__ dst, int* __restrict__ deg) {
  const int e = blockIdx.x * 256 + threadIdx.x;
  if (e < N_EDGES) atomicAdd(&deg[dst[e]], 1);
}

#define SCAN_T 1024
#define SCAN_CHUNK ((N_PAD + SCAN_T - 1) / SCAN_T)
__global__ __launch_bounds__(SCAN_T)
void scan_kernel(const int* __restrict__ deg,
                 int* __restrict__ row_ptr,
                 int* __restrict__ cursor) {
  __shared__ int part[SCAN_T];
  const int t = threadIdx.x;
  const int lo = t * SCAN_CHUNK;
  const int hi = min(lo + SCAN_CHUNK, N_PAD);
  int s = 0;
  for (int i = lo; i < hi; ++i) s += deg[i];
  part[t] = s;
  __syncthreads();
  for (int off = 1; off < SCAN_T; off <<= 1) {
    int v = (t >= off) ? part[t - off] : 0;
    __syncthreads();
    part[t] += v;
    __syncthreads();
  }
  int run = (t > 0) ? part[t - 1] : 0;
  for (int i = lo; i < hi; ++i) {
    row_ptr[i] = run;
    cursor[i] = run;
    run += deg[i];
  }
  if (t == SCAN_T - 1) row_ptr[N_PAD] = part[SCAN_T - 1];
}

__global__ void sort_kernel(const int* __restrict__ src,
                            const int* __restrict__ dst,
                            int* __restrict__ cursor,
                            int* __restrict__ sorted_src) {
  const int e = blockIdx.x * 256 + threadIdx.x;
  const int d = dst[e];
  const int pos = atomicAdd(&cursor[d], 1);
  sorted_src[pos] = src[e];
}

// ---------------- shared device pieces ----------------

// Aggregation phase: this block's 64 nodes [r0, r0+64); each 16-lane group
// accumulates one node at a time (4 concurrent per wave, 4 rounds).
// Result tile (bf16) lands in xs in GEMM staging layout.
__device__ __forceinline__ void agg_phase(const unsigned short* __restrict__ A,
                                          const unsigned short* __restrict__ B,
                                          const int* __restrict__ row_ptr,
                                          const int* __restrict__ sorted_src,
                                          unsigned short* xs, int r0, int t) {
  const int w = t >> 6, l = t & 63;
  const int lane16 = l & 15;
  const int g = l >> 4;
#pragma unroll
  for (int i = 0; i < 4; ++i) {
    const int nl = w * 16 + i * 4 + g;       // 0..63
    const int n = r0 + nl;
    const int beg = row_ptr[n];
    const int end = row_ptr[n + 1];
    us8 av = *(const us8*)(A + (size_t)n * DF + lane16 * 8);
    float af[8];
#pragma unroll
    for (int j = 0; j < 8; ++j) af[j] = bf2f(av[j]);
    float acc[8] = {};
    int k = beg;
    for (; k + 4 <= end; k += 4) {
      const int s0 = sorted_src[k + 0];
      const int s1 = sorted_src[k + 1];
      const int s2 = sorted_src[k + 2];
      const int s3 = sorted_src[k + 3];
      us8 b0 = *(const us8*)(B + (size_t)s0 * DF + lane16 * 8);
      us8 b1 = *(const us8*)(B + (size_t)s1 * DF + lane16 * 8);
      us8 b2 = *(const us8*)(B + (size_t)s2 * DF + lane16 * 8);
      us8 b3 = *(const us8*)(B + (size_t)s3 * DF + lane16 * 8);
#pragma unroll
      for (int j = 0; j < 8; ++j) {
        float v0 = af[j] + bf2f(b0[j]);
        float v1 = af[j] + bf2f(b1[j]);
        float v2 = af[j] + bf2f(b2[j]);
        float v3 = af[j] + bf2f(b3[j]);
        acc[j] += (v0 > 0.f ? v0 : 0.f) + (v1 > 0.f ? v1 : 0.f)
                + (v2 > 0.f ? v2 : 0.f) + (v3 > 0.f ? v3 : 0.f);
      }
    }
    for (; k < end; ++k) {
      const int s = sorted_src[k];
      us8 bv = *(const us8*)(B + (size_t)s * DF + lane16 * 8);
#pragma unroll
      for (int j = 0; j < 8; ++j) {
        float v = af[j] + bf2f(bv[j]);
        acc[j] += v > 0.f ? v : 0.f;
      }
    }
    us8 o;
#pragma unroll
    for (int j = 0; j < 8; ++j) o[j] = f2bf(acc[j]);
    *(us8*)&xs[nl * HS + lane16 * 8] = o;
  }
}

// ---------------- kernels ----------------

// Layer-1 dual GEMM: A1 = x@Wa1 + b1_0, B1 = x@Wb1   (x fp32)
__global__ __launch_bounds__(256)
void dual_gemm_x(const float* __restrict__ in,
                 const unsigned short* __restrict__ wpA,
                 const unsigned short* __restrict__ wpB,
                 const float* __restrict__ bcA,
                 unsigned short* __restrict__ outA,
                 unsigned short* __restrict__ outB) {
  __shared__ unsigned short xs[64 * HS];
  const int t = threadIdx.x;
  const int r0 = blockIdx.x * 64;
  {
    const int e = t >> 2, q = t & 3;
    const int grow = r0 + e;
    const float4* src = (const float4*)(in + (size_t)grow * DF) + q * 8;
#pragma unroll
    for (int i = 0; i < 8; ++i) {
      float4 v = { 0.f, 0.f, 0.f, 0.f };
      if (grow < N_NODES) v = src[i];
      us4 p = { f2bf(v.x), f2bf(v.y), f2bf(v.z), f2bf(v.w) };
      *(us4*)&xs[e * HS + q * 32 + i * 4] = p;
    }
  }
  __syncthreads();

  const int w = t >> 6, l = t & 63, l15 = l & 15, lg = l >> 4;
  f32x4 accA[4][2] = {};
  f32x4 accB[4][2] = {};
  const uint4v* wvA = (const uint4v*)wpA;
  const uint4v* wvB = (const uint4v*)wpB;
#pragma unroll
  for (int kc = 0; kc < 4; ++kc) {
    bf16x8 afr[4];
#pragma unroll
    for (int rt = 0; rt < 4; ++rt)
      afr[rt] = __builtin_bit_cast(bf16x8,
          *(const uint4v*)&xs[(rt * 16 + l15) * HS + kc * 32 + lg * 8]);
#pragma unroll
    for (int c = 0; c < 2; ++c) {
      bf16x8 bfrA = __builtin_bit_cast(bf16x8, wvA[((w * 2 + c) * 4 + kc) * 64 + l]);
      bf16x8 bfrB = __builtin_bit_cast(bf16x8, wvB[((w * 2 + c) * 4 + kc) * 64 + l]);
#pragma unroll
      for (int rt = 0; rt < 4; ++rt) {
        accA[rt][c] = __builtin_amdgcn_mfma_f32_16x16x32_bf16(afr[rt], bfrA, accA[rt][c], 0, 0, 0);
        accB[rt][c] = __builtin_amdgcn_mfma_f32_16x16x32_bf16(afr[rt], bfrB, accB[rt][c], 0, 0, 0);
      }
    }
  }
#pragma unroll
  for (int c = 0; c < 2; ++c) {
    const int col = w * 32 + c * 16 + l15;
    const float cA = bcA[col];
#pragma unroll
    for (int rt = 0; rt < 4; ++rt) {
#pragma unroll
      for (int r = 0; r < 4; ++r) {
        const int grow = r0 + rt * 16 + lg * 4 + r;
        outA[(size_t)grow * DF + col] = f2bf(accA[rt][c][r] + cA);
        outB[(size_t)grow * DF + col] = f2bf(accB[rt][c][r]);
      }
    }
  }
}

// Fused: Hsum1 aggregation (in LDS) + dual GEMM with combined weights:
//   A2 = Hsum1@W20A + b1_1 + deg*vA,  B2 = Hsum1@W20B + deg*vB
__global__ __launch_bounds__(256)
void agg_dual(const unsigned short* __restrict__ A,
              const unsigned short* __restrict__ B,
              const int* __restrict__ row_ptr,
              const int* __restrict__ sorted_src,
              const unsigned short* __restrict__ wpA,
              const unsigned short* __restrict__ wpB,
              const float* __restrict__ bcA, const float* __restrict__ bdA,
              const float* __restrict__ bdB,
              const int* __restrict__ deg,
              unsigned short* __restrict__ outA,
              unsigned short* __restrict__ outB) {
  __shared__ unsigned short xs[64 * HS];
  const int t = threadIdx.x;
  const int r0 = blockIdx.x * 64;

  agg_phase(A, B, row_ptr, sorted_src, xs, r0, t);
  __syncthreads();

  const int w = t >> 6, l = t & 63, l15 = l & 15, lg = l >> 4;
  f32x4 accA[4][2] = {};
  f32x4 accB[4][2] = {};
  const uint4v* wvA = (const uint4v*)wpA;
  const uint4v* wvB = (const uint4v*)wpB;
#pragma unroll
  for (int kc = 0; kc < 4; ++kc) {
    bf16x8 afr[4];
#pragma unroll
    for (int rt = 0; rt < 4; ++rt)
      afr[rt] = __builtin_bit_cast(bf16x8,
          *(const uint4v*)&xs[(rt * 16 + l15) * HS + kc * 32 + lg * 8]);
#pragma unroll
    for (int c = 0; c < 2; ++c) {
      bf16x8 bfrA = __builtin_bit_cast(bf16x8, wvA[((w * 2 + c) * 4 + kc) * 64 + l]);
      bf16x8 bfrB = __builtin_bit_cast(bf16x8, wvB[((w * 2 + c) * 4 + kc) * 64 + l]);
#pragma unroll
      for (int rt = 0; rt < 4; ++rt) {
        accA[rt][c] = __builtin_amdgcn_mfma_f32_16x16x32_bf16(afr[rt], bfrA, accA[rt][c], 0, 0, 0);
        accB[rt][c] = __builtin_amdgcn_mfma_f32_16x16x32_bf16(afr[rt], bfrB, accB[rt][c], 0, 0, 0);
      }
    }
  }
#pragma unroll
  for (int c = 0; c < 2; ++c) {
    const int col = w * 32 + c * 16 + l15;
    const float cA = bcA[col];
    const float dA = bdA[col];
    const float dB = bdB[col];
#pragma unroll
    for (int rt = 0; rt < 4; ++rt) {
#pragma unroll
      for (int r = 0; r < 4; ++r) {
        const int grow = r0 + rt * 16 + lg * 4 + r;
        const float dg = (float)deg[grow];
        outA[(size_t)grow * DF + col] = f2bf(accA[rt][c][r] + cA + dg * dA);
        outB[(size_t)grow * DF + col] = f2bf(accB[rt][c][r] + dg * dB);
      }
    }
  }
}

// Fused: Hsum2 aggregation (in LDS) + GEMM -> feat2 = Hsum2@W21 + deg*b2_1
// (fp32, non-temporal stores; never re-read).
__global__ __launch_bounds__(256)
void agg_gemm_out(const unsigned short* __restrict__ A,
                  const unsigned short* __restrict__ B,
                  const int* __restrict__ row_ptr,
                  const int* __restrict__ sorted_src,
                  const unsigned short* __restrict__ wp,
                  const float* __restrict__ bd,
                  const int* __restrict__ deg,
                  float* __restrict__ out) {
  __shared__ unsigned short xs[64 * HS];
  const int t = threadIdx.x;
  const int r0 = blockIdx.x * 64;

  agg_phase(A, B, row_ptr, sorted_src, xs, r0, t);
  __syncthreads();

  const int w = t >> 6, l = t & 63, l15 = l & 15, lg = l >> 4;
  f32x4 acc[4][2] = {};
  const uint4v* wv = (const uint4v*)wp;
#pragma unroll
  for (int kc = 0; kc < 4; ++kc) {
    bf16x8 afr[4];
#pragma unroll
    for (int rt = 0; rt < 4; ++rt)
      afr[rt] = __builtin_bit_cast(bf16x8,
          *(const uint4v*)&xs[(rt * 16 + l15) * HS + kc * 32 + lg * 8]);
#pragma unroll
    for (int c = 0; c < 2; ++c) {
      bf16x8 bfr = __builtin_bit_cast(bf16x8, wv[((w * 2 + c) * 4 + kc) * 64 + l]);
#pragma unroll
      for (int rt = 0; rt < 4; ++rt)
        acc[rt][c] = __builtin_amdgcn_mfma_f32_16x16x32_bf16(afr[rt], bfr, acc[rt][c], 0, 0, 0);
    }
  }
#pragma unroll
  for (int c = 0; c < 2; ++c) {
    const int col = w * 32 + c * 16 + l15;
    const float bv = bd[col];
#pragma unroll
    for (int rt = 0; rt < 4; ++rt) {
#pragma unroll
      for (int r = 0; r < 4; ++r) {
        const int grow = r0 + rt * 16 + lg * 4 + r;
        if (grow < N_NODES) {
          const float v = acc[rt][c][r] + (float)deg[grow] * bv;
          __builtin_nontemporal_store(v, &out[(size_t)grow * DF + col]);
        }
      }
    }
  }
}

// Layer-2 per-edge GEMM (original order, coalesced, non-temporal msg writes).
__global__ __launch_bounds__(256)
void edge_msg(const unsigned short* __restrict__ A,
              const unsigned short* __restrict__ B,
              const int* __restrict__ src,
              const int* __restrict__ dst,
              const unsigned short* __restrict__ w2p,
              const float* __restrict__ b2,
              float* __restrict__ msg_out) {
  __shared__ unsigned short h_s[64 * HS];
  const int t = threadIdx.x;
  const int e0 = blockIdx.x * 64;

  {
    const int e = t >> 2, q = t & 3;
    const int ge = e0 + e;
    const int si = src[ge];
    const int di = dst[ge];
    const us8* ap = (const us8*)(A + (size_t)di * DF + q * 32);
    const us8* bp = (const us8*)(B + (size_t)si * DF + q * 32);
    us8 av[4], bv[4];
#pragma unroll
    for (int i = 0; i < 4; ++i) { av[i] = ap[i]; bv[i] = bp[i]; }
#pragma unroll
    for (int i = 0; i < 4; ++i) {
      us8 h;
#pragma unroll
      for (int j = 0; j < 8; ++j) {
        float v = bf2f(av[i][j]) + bf2f(bv[i][j]);
        v = v > 0.f ? v : 0.f;
        h[j] = f2bf(v);
      }
      *(us8*)&h_s[e * HS + q * 32 + i * 8] = h;
    }
  }
  __syncthreads();

  const int w = t >> 6, l = t & 63, l15 = l & 15, lg = l >> 4;
  f32x4 acc[4][2] = {};
  const uint4v* wv = (const uint4v*)w2p;
#pragma unroll
  for (int kc = 0; kc < 4; ++kc) {
    bf16x8 afr[4];
#pragma unroll
    for (int rt = 0; rt < 4; ++rt)
      afr[rt] = __builtin_bit_cast(bf16x8,
          *(const uint4v*)&h_s[(rt * 16 + l15) * HS + kc * 32 + lg * 8]);
#pragma unroll
    for (int c = 0; c < 2; ++c) {
      bf16x8 bfr = __builtin_bit_cast(bf16x8, wv[((w * 2 + c) * 4 + kc) * 64 + l]);
#pragma unroll
      for (int rt = 0; rt < 4; ++rt)
        acc[rt][c] = __builtin_amdgcn_mfma_f32_16x16x32_bf16(afr[rt], bfr, acc[rt][c], 0, 0, 0);
    }
  }

#pragma unroll
  for (int c = 0; c < 2; ++c) {
    const int col = w * 32 + c * 16 + l15;
    const float bv = b2[col];
#pragma unroll
    for (int rt = 0; rt < 4; ++rt) {
#pragma unroll
      for (int r = 0; r < 4; ++r) {
        const int row = rt * 16 + lg * 4 + r;
        __builtin_nontemporal_store(acc[rt][c][r] + bv,
                                    &msg_out[(size_t)(e0 + row) * DF + col]);
      }
    }
  }
}

extern "C" void kernel_launch(void* const* d_in, const int* in_sizes, int n_in,
                              void* d_out, int out_size, void* d_ws, size_t ws_size,
                              hipStream_t stream) {
  const float* x    = (const float*)d_in[0];
  const int*   eidx = (const int*)d_in[1];
  const float* W1_0 = (const float*)d_in[2];
  const float* b1_0 = (const float*)d_in[3];
  const float* W2_0 = (const float*)d_in[4];
  const float* b2_0 = (const float*)d_in[5];
  const float* W1_1 = (const float*)d_in[6];
  const float* b1_1 = (const float*)d_in[7];
  const float* W2_1 = (const float*)d_in[8];
  const float* b2_1 = (const float*)d_in[9];

  const int* src = eidx;
  const int* dst = eidx + N_EDGES;

  float* feat2 = (float*)d_out;
  float* msg2  = feat2 + (size_t)N_NODES * DF;

  // ---- workspace layout ----
  char* ws = (char*)d_ws;
  const size_t BF_ROWS = (size_t)N_PAD * DF;
  unsigned short* A1 = (unsigned short*)ws;  ws += BF_ROWS * 2;   // 12.8 MB
  unsigned short* B1 = (unsigned short*)ws;  ws += BF_ROWS * 2;   // 12.8 MB
  unsigned short* A2 = (unsigned short*)ws;  ws += BF_ROWS * 2;   // 12.8 MB
  unsigned short* B2 = (unsigned short*)ws;  ws += BF_ROWS * 2;   // 12.8 MB
  int* deg        = (int*)ws;  ws += (size_t)N_PAD * 4;
  int* row_ptr    = (int*)ws;  ws += (size_t)(N_PAD + 1) * 4;
  int* cursor     = (int*)ws;  ws += (size_t)N_PAD * 4;
  int* sorted_src = (int*)ws;  ws += (size_t)N_EDGES * 4;         // 3.2 MB
  float* W20A_f = (float*)ws;  ws += 16384 * 4;
  float* W20B_f = (float*)ws;  ws += 16384 * 4;
  float* vA     = (float*)ws;  ws += 128 * 4;
  float* vB     = (float*)ws;  ws += 128 * 4;
  unsigned short* wa1p  = (unsigned short*)ws;  ws += 16384 * 2;
  unsigned short* wb1p  = (unsigned short*)ws;  ws += 16384 * 2;
  unsigned short* w21p  = (unsigned short*)ws;  ws += 16384 * 2;
  unsigned short* w20Ap = (unsigned short*)ws;  ws += 16384 * 2;
  unsigned short* w20Bp = (unsigned short*)ws;  ws += 16384 * 2;

  hipMemsetAsync(deg, 0, (size_t)N_PAD * 4, stream);

  // Weight prep. W1 rows 0..127 multiply x_i, rows 128..255 multiply (x_j-x_i):
  // Wa = top - bot (applies to x_i = x[dst]), Wb = bot (applies to x_j = x[src]).
  wcomb_kernel<<<129, 256, 0, stream>>>(W2_0, W1_1, b2_0, W20A_f, W20B_f, vA, vB);
  pack_all<<<40, 256, 0, stream>>>(W1_0, W2_1, W20A_f, W20B_f,
                                   wa1p, wb1p, w21p, w20Ap, w20Bp);

  // CSR build
  deg_kernel<<<N_EDGES / 256, 256, 0, stream>>>(dst, deg);
  scan_kernel<<<1, SCAN_T, 0, stream>>>(deg, row_ptr, cursor);
  sort_kernel<<<N_EDGES / 256, 256, 0, stream>>>(src, dst, cursor, sorted_src);

  const int NG = N_PAD / 64;   // 782

  // Layer 1: A1 = x@Wa1 + b1_0,  B1 = x@Wb1
  dual_gemm_x<<<NG, 256, 0, stream>>>(x, wa1p, wb1p, b1_0, A1, B1);

  // Fused aggregate(Hsum1) + combined-weight dual GEMM -> A2, B2
  agg_dual<<<NG, 256, 0, stream>>>(A1, B1, row_ptr, sorted_src,
                                   w20Ap, w20Bp, b1_1, vA, vB, deg, A2, B2);

  // msg2 in original edge order (coalesced nt-writes)
  edge_msg<<<N_EDGES / 64, 256, 0, stream>>>(A2, B2, src, dst, w21p, b2_1, msg2);

  // Fused aggregate(Hsum2) + GEMM -> feat2 (nt-writes)
  agg_gemm_out<<<NG, 256, 0, stream>>>(A2, B2, row_ptr, sorted_src,
                                       w21p, b2_1, deg, feat2);
}

// Round 9
// 476.966 us; speedup vs baseline: 1.1320x; 1.0570x over previous
//
#include <hip/hip_runtime.h>
#include <hip/hip_bf16.h>

#define N_NODES 50000
#define N_PAD   50048      // 64-row multiple for guard-free GEMM tiles
#define N_EDGES 800000
#define DF 128
#define NG (N_PAD / 64)    // 782 node-GEMM blocks
#define DEG_BLOCKS (N_EDGES / 256)  // 3125

// LDS row stride (ushorts): 128 bf16 + 8 pad (272 B = 17*16 B)
#define HS 136

typedef __bf16 bf16x8 __attribute__((ext_vector_type(8)));
typedef float f32x4 __attribute__((ext_vector_type(4)));
typedef unsigned int uint4v __attribute__((ext_vector_type(4)));
typedef unsigned short us4 __attribute__((ext_vector_type(4)));
typedef unsigned short us8 __attribute__((ext_vector_type(8)));

__device__ __forceinline__ unsigned short f2bf(float f) {
  unsigned u = __builtin_bit_cast(unsigned, f);
  u += 0x7FFFu + ((u >> 16) & 1u);   // RNE
  return (unsigned short)(u >> 16);
}
__device__ __forceinline__ float bf2f(unsigned short u) {
  return __builtin_bit_cast(float, ((unsigned)u) << 16);
}

// ---------------- weight prep (proven r4-r6) ----------------

__global__ void wcomb_kernel(const float* __restrict__ W2_0,
                             const float* __restrict__ W1_1,
                             const float* __restrict__ b2_0,
                             float* __restrict__ W20A,
                             float* __restrict__ W20B,
                             float* __restrict__ vA,
                             float* __restrict__ vB) {
  const int b = blockIdx.x;
  const int t = threadIdx.x;
  const int c = t & 127;
  const bool isB = t >= 128;
  float acc = 0.f;
  if (b < 128) {
    const float* wrow = W2_0 + (size_t)b * DF;
    for (int k = 0; k < 128; ++k) {
      float bot = W1_1[(size_t)(128 + k) * DF + c];
      float w = isB ? bot : (W1_1[(size_t)k * DF + c] - bot);
      acc += wrow[k] * w;
    }
    if (isB) W20B[(size_t)b * DF + c] = acc;
    else     W20A[(size_t)b * DF + c] = acc;
  } else {
    for (int k = 0; k < 128; ++k) {
      float bot = W1_1[(size_t)(128 + k) * DF + c];
      float w = isB ? bot : (W1_1[(size_t)k * DF + c] - bot);
      acc += b2_0[k] * w;
    }
    if (isB) vB[c] = acc;
    else     vA[c] = acc;
  }
}

__global__ void pack_all(const float* __restrict__ W1_0,
                         const float* __restrict__ W2_1,
                         const float* __restrict__ W20A_f,
                         const float* __restrict__ W20B_f,
                         unsigned short* __restrict__ wa1p,
                         unsigned short* __restrict__ wb1p,
                         unsigned short* __restrict__ w21p,
                         unsigned short* __restrict__ w20Ap,
                         unsigned short* __restrict__ w20Bp) {
  const int mat = blockIdx.x >> 3;
  const int idx = (blockIdx.x & 7) * 256 + threadIdx.x;   // < 2048
  const int l = idx & 63;
  const int blk = idx >> 6;
  const int ct = blk >> 2;
  const int kc = blk & 3;
  const int col = ct * 16 + (l & 15);
  const int k0 = kc * 32 + (l >> 4) * 8;
  const float* W;
  const float* Wsub = nullptr;
  unsigned short* out;
  switch (mat) {
    case 0: W = W1_0;            Wsub = W1_0 + 128 * DF; out = wa1p;  break;
    case 1: W = W1_0 + 128 * DF;                         out = wb1p;  break;
    case 2: W = W2_1;                                    out = w21p;  break;
    case 3: W = W20A_f;                                  out = w20Ap; break;
    default: W = W20B_f;                                 out = w20Bp; break;
  }
  unsigned short tmp[8];
#pragma unroll
  for (int j = 0; j < 8; ++j) {
    float v = W[(size_t)(k0 + j) * DF + col];
    if (Wsub) v -= Wsub[(size_t)(k0 + j) * DF + col];
    tmp[j] = f2bf(v);
  }
  us4 lo = { tmp[0], tmp[1], tmp[2], tmp[3] };
  us4 hi = { tmp[4], tmp[5], tmp[6], tmp[7] };
  us4* o = (us4*)(out + (size_t)idx * 8);
  o[0] = lo;
  o[1] = hi;
}

// ---------------- CSR build (proven) ----------------

__global__ void deg_kernel(const int* __restrict__ dst, int* __restrict__ deg) {
  const int e = blockIdx.x * 256 + threadIdx.x;
  if (e < N_EDGES) atomicAdd(&deg[dst[e]], 1);
}

#define SCAN_T 1024
#define SCAN_CHUNK ((N_PAD + SCAN_T - 1) / SCAN_T)
__global__ __launch_bounds__(SCAN_T)
void scan_kernel(const int* __restrict__ deg,
                 int* __restrict__ row_ptr,
                 int* __restrict__ cursor) {
  __shared__ int part[SCAN_T];
  const int t = threadIdx.x;
  const int lo = t * SCAN_CHUNK;
  const int hi = min(lo + SCAN_CHUNK, N_PAD);
  int s = 0;
  for (int i = lo; i < hi; ++i) s += deg[i];
  part[t] = s;
  __syncthreads();
  for (int off = 1; off < SCAN_T; off <<= 1) {
    int v = (t >= off) ? part[t - off] : 0;
    __syncthreads();
    part[t] += v;
    __syncthreads();
  }
  int run = (t > 0) ? part[t - 1] : 0;
  for (int i = lo; i < hi; ++i) {
    row_ptr[i] = run;
    cursor[i] = run;
    run += deg[i];
  }
  if (t == SCAN_T - 1) row_ptr[N_PAD] = part[SCAN_T - 1];
}

__global__ void sort_kernel(const int* __restrict__ src,
                            const int* __restrict__ dst,
                            int* __restrict__ cursor,
                            int* __restrict__ sorted_src,
                            int* __restrict__ sorted_dst,
                            int* __restrict__ sorted_eid) {
  const int e = blockIdx.x * 256 + threadIdx.x;
  const int d = dst[e];
  const int pos = atomicAdd(&cursor[d], 1);
  sorted_src[pos] = src[e];
  sorted_dst[pos] = d;
  sorted_eid[pos] = e;
}

// ---------------- shared device pieces (proven r6) ----------------

__device__ __forceinline__ void agg_phase(const unsigned short* __restrict__ A,
                                          const unsigned short* __restrict__ B,
                                          const int* __restrict__ row_ptr,
                                          const int* __restrict__ sorted_src,
                                          unsigned short* xs, int r0, int t) {
  const int w = t >> 6, l = t & 63;
  const int lane16 = l & 15;
  const int g = l >> 4;
#pragma unroll
  for (int i = 0; i < 4; ++i) {
    const int nl = w * 16 + i * 4 + g;       // 0..63
    const int n = r0 + nl;
    const int beg = row_ptr[n];
    const int end = row_ptr[n + 1];
    us8 av = *(const us8*)(A + (size_t)n * DF + lane16 * 8);
    float af[8];
#pragma unroll
    for (int j = 0; j < 8; ++j) af[j] = bf2f(av[j]);
    float acc[8] = {};
    int k = beg;
    for (; k + 4 <= end; k += 4) {
      const int s0 = sorted_src[k + 0];
      const int s1 = sorted_src[k + 1];
      const int s2 = sorted_src[k + 2];
      const int s3 = sorted_src[k + 3];
      us8 b0 = *(const us8*)(B + (size_t)s0 * DF + lane16 * 8);
      us8 b1 = *(const us8*)(B + (size_t)s1 * DF + lane16 * 8);
      us8 b2 = *(const us8*)(B + (size_t)s2 * DF + lane16 * 8);
      us8 b3 = *(const us8*)(B + (size_t)s3 * DF + lane16 * 8);
#pragma unroll
      for (int j = 0; j < 8; ++j) {
        float v0 = af[j] + bf2f(b0[j]);
        float v1 = af[j] + bf2f(b1[j]);
        float v2 = af[j] + bf2f(b2[j]);
        float v3 = af[j] + bf2f(b3[j]);
        acc[j] += (v0 > 0.f ? v0 : 0.f) + (v1 > 0.f ? v1 : 0.f)
                + (v2 > 0.f ? v2 : 0.f) + (v3 > 0.f ? v3 : 0.f);
      }
    }
    for (; k < end; ++k) {
      const int s = sorted_src[k];
      us8 bv = *(const us8*)(B + (size_t)s * DF + lane16 * 8);
#pragma unroll
      for (int j = 0; j < 8; ++j) {
        float v = af[j] + bf2f(bv[j]);
        acc[j] += v > 0.f ? v : 0.f;
      }
    }
    us8 o;
#pragma unroll
    for (int j = 0; j < 8; ++j) o[j] = f2bf(acc[j]);
    *(us8*)&xs[nl * HS + lane16 * 8] = o;
  }
}

// ---------------- kernels ----------------

// Layer-1 dual GEMM: A1 = x@Wa1 + b1_0, B1 = x@Wb1   (proven r6)
__global__ __launch_bounds__(256)
void dual_gemm_x(const float* __restrict__ in,
                 const unsigned short* __restrict__ wpA,
                 const unsigned short* __restrict__ wpB,
                 const float* __restrict__ bcA,
                 unsigned short* __restrict__ outA,
                 unsigned short* __restrict__ outB) {
  __shared__ unsigned short xs[64 * HS];
  const int t = threadIdx.x;
  const int r0 = blockIdx.x * 64;
  {
    const int e = t >> 2, q = t & 3;
    const int grow = r0 + e;
    const float4* src = (const float4*)(in + (size_t)grow * DF) + q * 8;
#pragma unroll
    for (int i = 0; i < 8; ++i) {
      float4 v = { 0.f, 0.f, 0.f, 0.f };
      if (grow < N_NODES) v = src[i];
      us4 p = { f2bf(v.x), f2bf(v.y), f2bf(v.z), f2bf(v.w) };
      *(us4*)&xs[e * HS + q * 32 + i * 4] = p;
    }
  }
  __syncthreads();

  const int w = t >> 6, l = t & 63, l15 = l & 15, lg = l >> 4;
  f32x4 accA[4][2] = {};
  f32x4 accB[4][2] = {};
  const uint4v* wvA = (const uint4v*)wpA;
  const uint4v* wvB = (const uint4v*)wpB;
#pragma unroll
  for (int kc = 0; kc < 4; ++kc) {
    bf16x8 afr[4];
#pragma unroll
    for (int rt = 0; rt < 4; ++rt)
      afr[rt] = __builtin_bit_cast(bf16x8,
          *(const uint4v*)&xs[(rt * 16 + l15) * HS + kc * 32 + lg * 8]);
#pragma unroll
    for (int c = 0; c < 2; ++c) {
      bf16x8 bfrA = __builtin_bit_cast(bf16x8, wvA[((w * 2 + c) * 4 + kc) * 64 + l]);
      bf16x8 bfrB = __builtin_bit_cast(bf16x8, wvB[((w * 2 + c) * 4 + kc) * 64 + l]);
#pragma unroll
      for (int rt = 0; rt < 4; ++rt) {
        accA[rt][c] = __builtin_amdgcn_mfma_f32_16x16x32_bf16(afr[rt], bfrA, accA[rt][c], 0, 0, 0);
        accB[rt][c] = __builtin_amdgcn_mfma_f32_16x16x32_bf16(afr[rt], bfrB, accB[rt][c], 0, 0, 0);
      }
    }
  }
#pragma unroll
  for (int c = 0; c < 2; ++c) {
    const int col = w * 32 + c * 16 + l15;
    const float cA = bcA[col];
#pragma unroll
    for (int rt = 0; rt < 4; ++rt) {
#pragma unroll
      for (int r = 0; r < 4; ++r) {
        const int grow = r0 + rt * 16 + lg * 4 + r;
        outA[(size_t)grow * DF + col] = f2bf(accA[rt][c][r] + cA);
        outB[(size_t)grow * DF + col] = f2bf(accB[rt][c][r]);
      }
    }
  }
}

// Fused: Hsum1 aggregation (LDS) + combined-weight dual GEMM -> A2, B2 (proven r6)
__global__ __launch_bounds__(256)
void agg_dual(const unsigned short* __restrict__ A,
              const unsigned short* __restrict__ B,
              const int* __restrict__ row_ptr,
              const int* __restrict__ sorted_src,
              const unsigned short* __restrict__ wpA,
              const unsigned short* __restrict__ wpB,
              const float* __restrict__ bcA, const float* __restrict__ bdA,
              const float* __restrict__ bdB,
              const int* __restrict__ deg,
              unsigned short* __restrict__ outA,
              unsigned short* __restrict__ outB) {
  __shared__ unsigned short xs[64 * HS];
  const int t = threadIdx.x;
  const int r0 = blockIdx.x * 64;

  agg_phase(A, B, row_ptr, sorted_src, xs, r0, t);
  __syncthreads();

  const int w = t >> 6, l = t & 63, l15 = l & 15, lg = l >> 4;
  f32x4 accA[4][2] = {};
  f32x4 accB[4][2] = {};
  const uint4v* wvA = (const uint4v*)wpA;
  const uint4v* wvB = (const uint4v*)wpB;
#pragma unroll
  for (int kc = 0; kc < 4; ++kc) {
    bf16x8 afr[4];
#pragma unroll
    for (int rt = 0; rt < 4; ++rt)
      afr[rt] = __builtin_bit_cast(bf16x8,
          *(const uint4v*)&xs[(rt * 16 + l15) * HS + kc * 32 + lg * 8]);
#pragma unroll
    for (int c = 0; c < 2; ++c) {
      bf16x8 bfrA = __builtin_bit_cast(bf16x8, wvA[((w * 2 + c) * 4 + kc) * 64 + l]);
      bf16x8 bfrB = __builtin_bit_cast(bf16x8, wvB[((w * 2 + c) * 4 + kc) * 64 + l]);
#pragma unroll
      for (int rt = 0; rt < 4; ++rt) {
        accA[rt][c] = __builtin_amdgcn_mfma_f32_16x16x32_bf16(afr[rt], bfrA, accA[rt][c], 0, 0, 0);
        accB[rt][c] = __builtin_amdgcn_mfma_f32_16x16x32_bf16(afr[rt], bfrB, accB[rt][c], 0, 0, 0);
      }
    }
  }
#pragma unroll
  for (int c = 0; c < 2; ++c) {
    const int col = w * 32 + c * 16 + l15;
    const float cA = bcA[col];
    const float dA = bdA[col];
    const float dB = bdB[col];
#pragma unroll
    for (int rt = 0; rt < 4; ++rt) {
#pragma unroll
      for (int r = 0; r < 4; ++r) {
        const int grow = r0 + rt * 16 + lg * 4 + r;
        const float dg = (float)deg[grow];
        outA[(size_t)grow * DF + col] = f2bf(accA[rt][c][r] + cA + dg * dA);
        outB[(size_t)grow * DF + col] = f2bf(accB[rt][c][r] + dg * dB);
      }
    }
  }
}

// Fused layer-2 edge kernel (round-4-proven segment scan + LDS-bounce msg write):
//  h = relu(A2[dst]+B2[src]) (LDS); Hsum2 via serial segmented column scan
//  (plain store interior, fp32 atomic at block boundaries);
//  msg[orig_eid] = h@W21 + b2_1 via LDS bounce, row-coalesced scalar nt stores.
__global__ __launch_bounds__(256)
void edge_fused2(const unsigned short* __restrict__ A,
                 const unsigned short* __restrict__ B,
                 const int* __restrict__ sorted_src,
                 const int* __restrict__ sorted_dst,
                 const int* __restrict__ sorted_eid,
                 const unsigned short* __restrict__ w2p,
                 const float* __restrict__ b2,
                 float* __restrict__ msg_out,
                 float* __restrict__ Hsum2) {
  __shared__ unsigned short h_s[64 * HS];
  __shared__ int node_s[64];
  __shared__ int eid_s[64];
  const int t = threadIdx.x;
  const int e0 = blockIdx.x * 64;

  // ---- stage h (round-4 proven)
  {
    const int e = t >> 2, q = t & 3;
    const int pos = e0 + e;
    const int si = sorted_src[pos];
    const int di = sorted_dst[pos];
    if (q == 0) { node_s[e] = di; eid_s[e] = sorted_eid[pos]; }
    const us8* ap = (const us8*)(A + (size_t)di * DF + q * 32);
    const us8* bp = (const us8*)(B + (size_t)si * DF + q * 32);
    us8 av[4], bv[4];
#pragma unroll
    for (int i = 0; i < 4; ++i) { av[i] = ap[i]; bv[i] = bp[i]; }
#pragma unroll
    for (int i = 0; i < 4; ++i) {
      us8 h;
#pragma unroll
      for (int j = 0; j < 8; ++j) {
        float v = bf2f(av[i][j]) + bf2f(bv[i][j]);
        v = v > 0.f ? v : 0.f;
        h[j] = f2bf(v);
      }
      *(us8*)&h_s[e * HS + q * 32 + i * 8] = h;
    }
  }
  __syncthreads();

  const int w = t >> 6, l = t & 63, l15 = l & 15, lg = l >> 4;

  // ---- main GEMM: msg = h @ W21 (proven)
  f32x4 acc[4][2] = {};
  const uint4v* wv = (const uint4v*)w2p;
#pragma unroll
  for (int kc = 0; kc < 4; ++kc) {
    bf16x8 afr[4];
#pragma unroll
    for (int rt = 0; rt < 4; ++rt)
      afr[rt] = __builtin_bit_cast(bf16x8,
          *(const uint4v*)&h_s[(rt * 16 + l15) * HS + kc * 32 + lg * 8]);
#pragma unroll
    for (int c = 0; c < 2; ++c) {
      bf16x8 bfr = __builtin_bit_cast(bf16x8, wv[((w * 2 + c) * 4 + kc) * 64 + l]);
#pragma unroll
      for (int rt = 0; rt < 4; ++rt)
        acc[rt][c] = __builtin_amdgcn_mfma_f32_16x16x32_bf16(afr[rt], bfr, acc[rt][c], 0, 0, 0);
    }
  }

  // ---- Hsum2: serial segmented column scan (round-4 PROVEN, verbatim)
  if (t < 128) {
    const int col = t;
    const int prev = (e0 > 0) ? sorted_dst[e0 - 1] : -1;
    const int next = (e0 + 64 < N_EDGES) ? sorted_dst[e0 + 64] : -1;
    int run_n = node_s[0];
    int run_a = 0;
    float racc = 0.f;
    for (int r = 0; r < 64; ++r) {
      const int n = node_s[r];
      if (n != run_n) {
        float* p = &Hsum2[(size_t)run_n * DF + col];
        if (run_a == 0 && prev == run_n) unsafeAtomicAdd(p, racc);
        else *p = racc;
        run_n = n; run_a = r; racc = 0.f;
      }
      racc += bf2f(h_s[r * HS + col]);
    }
    float* p = &Hsum2[(size_t)run_n * DF + col];
    if ((run_a == 0 && prev == run_n) || next == run_n) unsafeAtomicAdd(p, racc);
    else *p = racc;
  }
  __syncthreads();   // all h_s reads done

  // ---- msg tile (bf16) into h_s, then row-coalesced scalar nt scatter
#pragma unroll
  for (int c = 0; c < 2; ++c) {
    const int col = w * 32 + c * 16 + l15;
    const float bv = b2[col];
#pragma unroll
    for (int rt = 0; rt < 4; ++rt) {
#pragma unroll
      for (int r = 0; r < 4; ++r)
        h_s[(rt * 16 + lg * 4 + r) * HS + col] = f2bf(acc[rt][c][r] + bv);
    }
  }
  __syncthreads();

  {
    const int off = (t & 31) * 4;        // element offset within a 128-col row
    const int rbase = t >> 5;            // 0..7
#pragma unroll
    for (int p = 0; p < 8; ++p) {
      const int row = p * 8 + rbase;
      us4 hv = *(const us4*)&h_s[row * HS + off];
      float* dstp = msg_out + (size_t)eid_s[row] * DF + off;
      __builtin_nontemporal_store(bf2f(hv[0]), dstp + 0);
      __builtin_nontemporal_store(bf2f(hv[1]), dstp + 1);
      __builtin_nontemporal_store(bf2f(hv[2]), dstp + 2);
      __builtin_nontemporal_store(bf2f(hv[3]), dstp + 3);
    }
  }
}

// feat2 = Hsum2(fp32) @ W21 + deg*b2_1, scalar nt stores (proven pattern).
__global__ __launch_bounds__(256)
void gemm_out(const float* __restrict__ in,
              const unsigned short* __restrict__ wp,
              const float* __restrict__ bd,
              const int* __restrict__ deg,
              float* __restrict__ out) {
  __shared__ unsigned short xs[64 * HS];
  const int t = threadIdx.x;
  const int r0 = blockIdx.x * 64;
  {
    const int e = t >> 2, q = t & 3;
    const int grow = r0 + e;
    const float4* src = (const float4*)(in + (size_t)grow * DF) + q * 8;
#pragma unroll
    for (int i = 0; i < 8; ++i) {
      float4 v = src[i];
      us4 p = { f2bf(v.x), f2bf(v.y), f2bf(v.z), f2bf(v.w) };
      *(us4*)&xs[e * HS + q * 32 + i * 4] = p;
    }
  }
  __syncthreads();

  const int w = t >> 6, l = t & 63, l15 = l & 15, lg = l >> 4;
  f32x4 acc[4][2] = {};
  const uint4v* wv = (const uint4v*)wp;
#pragma unroll
  for (int kc = 0; kc < 4; ++kc) {
    bf16x8 afr[4];
#pragma unroll
    for (int rt = 0; rt < 4; ++rt)
      afr[rt] = __builtin_bit_cast(bf16x8,
          *(const uint4v*)&xs[(rt * 16 + l15) * HS + kc * 32 + lg * 8]);
#pragma unroll
    for (int c = 0; c < 2; ++c) {
      bf16x8 bfr = __builtin_bit_cast(bf16x8, wv[((w * 2 + c) * 4 + kc) * 64 + l]);
#pragma unroll
      for (int rt = 0; rt < 4; ++rt)
        acc[rt][c] = __builtin_amdgcn_mfma_f32_16x16x32_bf16(afr[rt], bfr, acc[rt][c], 0, 0, 0);
    }
  }
#pragma unroll
  for (int c = 0; c < 2; ++c) {
    const int col = w * 32 + c * 16 + l15;
    const float bv = bd[col];
#pragma unroll
    for (int rt = 0; rt < 4; ++rt) {
#pragma unroll
      for (int r = 0; r < 4; ++r) {
        const int grow = r0 + rt * 16 + lg * 4 + r;
        if (grow < N_NODES) {
          const float v = acc[rt][c][r] + (float)deg[grow] * bv;
          __builtin_nontemporal_store(v, &out[(size_t)grow * DF + col]);
        }
      }
    }
  }
}

extern "C" void kernel_launch(void* const* d_in, const int* in_sizes, int n_in,
                              void* d_out, int out_size, void* d_ws, size_t ws_size,
                              hipStream_t stream) {
  const float* x    = (const float*)d_in[0];
  const int*   eidx = (const int*)d_in[1];
  const float* W1_0 = (const float*)d_in[2];
  const float* b1_0 = (const float*)d_in[3];
  const float* W2_0 = (const float*)d_in[4];
  const float* b2_0 = (const float*)d_in[5];
  const float* W1_1 = (const float*)d_in[6];
  const float* b1_1 = (const float*)d_in[7];
  const float* W2_1 = (const float*)d_in[8];
  const float* b2_1 = (const float*)d_in[9];

  const int* src = eidx;
  const int* dst = eidx + N_EDGES;

  float* feat2 = (float*)d_out;
  float* msg2  = feat2 + (size_t)N_NODES * DF;

  // ---- workspace layout (~62 MB; Hsum2 aliases A1/B1, dead after agg_dual) ----
  char* ws = (char*)d_ws;
  const size_t BF_ROWS = (size_t)N_PAD * DF;
  unsigned short* A1 = (unsigned short*)ws;  ws += BF_ROWS * 2;   // 12.8 MB
  unsigned short* B1 = (unsigned short*)ws;  ws += BF_ROWS * 2;   // 12.8 MB
  unsigned short* A2 = (unsigned short*)ws;  ws += BF_ROWS * 2;   // 12.8 MB
  unsigned short* B2 = (unsigned short*)ws;  ws += BF_ROWS * 2;   // 12.8 MB
  float* Hsum2 = (float*)A1;                 // 25.6 MB alias over A1+B1
  int* deg        = (int*)ws;  ws += (size_t)N_PAD * 4;
  int* row_ptr    = (int*)ws;  ws += (size_t)(N_PAD + 1) * 4;
  int* cursor     = (int*)ws;  ws += (size_t)N_PAD * 4;
  int* sorted_src = (int*)ws;  ws += (size_t)N_EDGES * 4;         // 3.2 MB
  int* sorted_dst = (int*)ws;  ws += (size_t)N_EDGES * 4;         // 3.2 MB
  int* sorted_eid = (int*)ws;  ws += (size_t)N_EDGES * 4;         // 3.2 MB
  float* W20A_f = (float*)ws;  ws += 16384 * 4;
  float* W20B_f = (float*)ws;  ws += 16384 * 4;
  float* vA     = (float*)ws;  ws += 128 * 4;
  float* vB     = (float*)ws;  ws += 128 * 4;
  unsigned short* wa1p  = (unsigned short*)ws;  ws += 16384 * 2;
  unsigned short* wb1p  = (unsigned short*)ws;  ws += 16384 * 2;
  unsigned short* w21p  = (unsigned short*)ws;  ws += 16384 * 2;
  unsigned short* w20Ap = (unsigned short*)ws;  ws += 16384 * 2;
  unsigned short* w20Bp = (unsigned short*)ws;  ws += 16384 * 2;

  hipMemsetAsync(deg, 0, (size_t)N_PAD * 4, stream);

  // Weight prep. Wa = W1_top - W1_bot (applies to x_i=x[dst]); Wb = W1_bot (x_j).
  wcomb_kernel<<<129, 256, 0, stream>>>(W2_0, W1_1, b2_0, W20A_f, W20B_f, vA, vB);
  pack_all<<<40, 256, 0, stream>>>(W1_0, W2_1, W20A_f, W20B_f,
                                   wa1p, wb1p, w21p, w20Ap, w20Bp);

  // CSR build
  deg_kernel<<<DEG_BLOCKS, 256, 0, stream>>>(dst, deg);
  scan_kernel<<<1, SCAN_T, 0, stream>>>(deg, row_ptr, cursor);
  sort_kernel<<<DEG_BLOCKS, 256, 0, stream>>>(src, dst, cursor,
                                              sorted_src, sorted_dst, sorted_eid);

  // Layer 1: A1 = x@Wa1 + b1_0,  B1 = x@Wb1
  dual_gemm_x<<<NG, 256, 0, stream>>>(x, wa1p, wb1p, b1_0, A1, B1);

  // Fused aggregate(Hsum1) + combined-weight dual GEMM -> A2, B2
  agg_dual<<<NG, 256, 0, stream>>>(A1, B1, row_ptr, sorted_src,
                                   w20Ap, w20Bp, b1_1, vA, vB, deg, A2, B2);

  // A1/B1 now dead -> zero the aliased Hsum2 region (stream-ordered)
  hipMemsetAsync(Hsum2, 0, BF_ROWS * 4, stream);

  // Fused: msg2 (LDS-bounce coalesced nt scatter) + Hsum2 (serial segment scan)
  edge_fused2<<<N_EDGES / 64, 256, 0, stream>>>(A2, B2, sorted_src, sorted_dst,
                                                sorted_eid, w21p, b2_1, msg2, Hsum2);

  // feat2 = Hsum2@W21 + deg*b2_1  (no gather)
  gemm_out<<<NG, 256, 0, stream>>>(Hsum2, w21p, b2_1, deg, feat2);
}

// Round 10
// 469.118 us; speedup vs baseline: 1.1509x; 1.0167x over previous
//
#include <hip/hip_runtime.h>
#include <hip/hip_bf16.h>

#define N_NODES 50000
#define N_PAD   50048      // 64-row multiple for guard-free GEMM tiles
#define N_EDGES 800000
#define DF 128
#define NG (N_PAD / 64)    // 782 node-GEMM blocks
#define DEG_BLOCKS (N_EDGES / 256)  // 3125

// LDS row stride (ushorts): 128 bf16 + 8 pad (272 B = 17*16 B)
#define HS 136

typedef __bf16 bf16x8 __attribute__((ext_vector_type(8)));
typedef float f32x4 __attribute__((ext_vector_type(4)));
typedef unsigned int uint4v __attribute__((ext_vector_type(4)));
typedef unsigned short us4 __attribute__((ext_vector_type(4)));
typedef unsigned short us8 __attribute__((ext_vector_type(8)));

__device__ __forceinline__ unsigned short f2bf(float f) {
  unsigned u = __builtin_bit_cast(unsigned, f);
  u += 0x7FFFu + ((u >> 16) & 1u);   // RNE
  return (unsigned short)(u >> 16);
}
__device__ __forceinline__ float bf2f(unsigned short u) {
  return __builtin_bit_cast(float, ((unsigned)u) << 16);
}

// Packed-fragment offset for element (k,col) of a [128][128] matrix:
// matches pack layout out[((ct*4+kc)*64 + l)*8 + j].
__device__ __forceinline__ int pack_off(int k, int c) {
  return ((((c >> 4) * 4 + (k >> 5)) * 64) + ((k >> 3) & 3) * 16 + (c & 15)) * 8
         + (k & 7);
}

// ---------------- fused weight prep + deg histogram ----------------
// blocks 0..127   : row b of W20A/W20B = W2_0[b,:] @ (Wa2|Wb2), written DIRECTLY
//                   in packed bf16 fragment order (threads 0-127: A, 128-255: B)
// block 128       : vA/vB = b2_0 @ (Wa2|Wb2)  (fp32)
// blocks 129..152 : pack wa1p / wb1p / w21p from fp32 inputs (8 blocks each)
// blocks 153+     : deg histogram
__global__ __launch_bounds__(256)
void wprep_deg(const float* __restrict__ W2_0,
               const float* __restrict__ W1_1,
               const float* __restrict__ b2_0,
               const float* __restrict__ W1_0,
               const float* __restrict__ W2_1,
               unsigned short* __restrict__ w20Ap,
               unsigned short* __restrict__ w20Bp,
               float* __restrict__ vA,
               float* __restrict__ vB,
               unsigned short* __restrict__ wa1p,
               unsigned short* __restrict__ wb1p,
               unsigned short* __restrict__ w21p,
               const int* __restrict__ dst,
               int* __restrict__ deg) {
  const int b = blockIdx.x;
  const int t = threadIdx.x;

  if (b < 129) {                      // wcomb, direct-packed
    const int c = t & 127;
    const bool isB = t >= 128;
    float acc = 0.f;
    if (b < 128) {
      const float* wrow = W2_0 + (size_t)b * DF;
      for (int k = 0; k < 128; ++k) {
        float bot = W1_1[(size_t)(128 + k) * DF + c];
        float w = isB ? bot : (W1_1[(size_t)k * DF + c] - bot);
        acc += wrow[k] * w;
      }
      unsigned short* out = isB ? w20Bp : w20Ap;
      out[pack_off(b, c)] = f2bf(acc);
    } else {
      for (int k = 0; k < 128; ++k) {
        float bot = W1_1[(size_t)(128 + k) * DF + c];
        float w = isB ? bot : (W1_1[(size_t)k * DF + c] - bot);
        acc += b2_0[k] * w;
      }
      if (isB) vB[c] = acc;
      else     vA[c] = acc;
    }
    return;
  }

  if (b < 153) {                      // pack wa1p / wb1p / w21p
    const int mat = (b - 129) >> 3;
    const int idx = ((b - 129) & 7) * 256 + t;   // < 2048
    const int l = idx & 63;
    const int blk = idx >> 6;
    const int ct = blk >> 2;
    const int kc = blk & 3;
    const int col = ct * 16 + (l & 15);
    const int k0 = kc * 32 + (l >> 4) * 8;
    const float* W;
    const float* Wsub = nullptr;
    unsigned short* out;
    if (mat == 0)      { W = W1_0;            Wsub = W1_0 + 128 * DF; out = wa1p; }
    else if (mat == 1) { W = W1_0 + 128 * DF;                         out = wb1p; }
    else               { W = W2_1;                                    out = w21p; }
    unsigned short tmp[8];
#pragma unroll
    for (int j = 0; j < 8; ++j) {
      float v = W[(size_t)(k0 + j) * DF + col];
      if (Wsub) v -= Wsub[(size_t)(k0 + j) * DF + col];
      tmp[j] = f2bf(v);
    }
    us4 lo = { tmp[0], tmp[1], tmp[2], tmp[3] };
    us4 hi = { tmp[4], tmp[5], tmp[6], tmp[7] };
    us4* o = (us4*)(out + (size_t)idx * 8);
    o[0] = lo;
    o[1] = hi;
    return;
  }

  // deg histogram
  const int e = (b - 153) * 256 + t;
  if (e < N_EDGES) atomicAdd(&deg[dst[e]], 1);
}

// ---------------- CSR sort (proven) ----------------

__global__ void sort_kernel(const int* __restrict__ src,
                            const int* __restrict__ dst,
                            int* __restrict__ cursor,
                            int* __restrict__ sorted_src,
                            int* __restrict__ sorted_dst,
                            int* __restrict__ sorted_eid) {
  const int e = blockIdx.x * 256 + threadIdx.x;
  const int d = dst[e];
  const int pos = atomicAdd(&cursor[d], 1);
  sorted_src[pos] = src[e];
  sorted_dst[pos] = d;
  sorted_eid[pos] = e;
}

// ---------------- shared device pieces (proven r6/r9) ----------------

__device__ __forceinline__ void agg_phase(const unsigned short* __restrict__ A,
                                          const unsigned short* __restrict__ B,
                                          const int* __restrict__ row_ptr,
                                          const int* __restrict__ sorted_src,
                                          unsigned short* xs, int r0, int t) {
  const int w = t >> 6, l = t & 63;
  const int lane16 = l & 15;
  const int g = l >> 4;
#pragma unroll
  for (int i = 0; i < 4; ++i) {
    const int nl = w * 16 + i * 4 + g;       // 0..63
    const int n = r0 + nl;
    const int beg = row_ptr[n];
    const int end = row_ptr[n + 1];
    us8 av = *(const us8*)(A + (size_t)n * DF + lane16 * 8);
    float af[8];
#pragma unroll
    for (int j = 0; j < 8; ++j) af[j] = bf2f(av[j]);
    float acc[8] = {};
    int k = beg;
    for (; k + 4 <= end; k += 4) {
      const int s0 = sorted_src[k + 0];
      const int s1 = sorted_src[k + 1];
      const int s2 = sorted_src[k + 2];
      const int s3 = sorted_src[k + 3];
      us8 b0 = *(const us8*)(B + (size_t)s0 * DF + lane16 * 8);
      us8 b1 = *(const us8*)(B + (size_t)s1 * DF + lane16 * 8);
      us8 b2 = *(const us8*)(B + (size_t)s2 * DF + lane16 * 8);
      us8 b3 = *(const us8*)(B + (size_t)s3 * DF + lane16 * 8);
#pragma unroll
      for (int j = 0; j < 8; ++j) {
        float v0 = af[j] + bf2f(b0[j]);
        float v1 = af[j] + bf2f(b1[j]);
        float v2 = af[j] + bf2f(b2[j]);
        float v3 = af[j] + bf2f(b3[j]);
        acc[j] += (v0 > 0.f ? v0 : 0.f) + (v1 > 0.f ? v1 : 0.f)
                + (v2 > 0.f ? v2 : 0.f) + (v3 > 0.f ? v3 : 0.f);
      }
    }
    for (; k < end; ++k) {
      const int s = sorted_src[k];
      us8 bv = *(const us8*)(B + (size_t)s * DF + lane16 * 8);
#pragma unroll
      for (int j = 0; j < 8; ++j) {
        float v = af[j] + bf2f(bv[j]);
        acc[j] += v > 0.f ? v : 0.f;
      }
    }
    us8 o;
#pragma unroll
    for (int j = 0; j < 8; ++j) o[j] = f2bf(acc[j]);
    *(us8*)&xs[nl * HS + lane16 * 8] = o;
  }
}

// ---------------- kernels ----------------

// Fat kernel: block 0 = 256-thread exclusive scan (deg -> row_ptr/cursor);
// blocks 1..NG = layer-1 dual GEMM (independent of the scan).
#define SCH ((N_PAD + 255) / 256)   // 196
__global__ __launch_bounds__(256)
void scan_gemm1(const int* __restrict__ deg,
                int* __restrict__ row_ptr,
                int* __restrict__ cursor,
                const float* __restrict__ in,
                const unsigned short* __restrict__ wpA,
                const unsigned short* __restrict__ wpB,
                const float* __restrict__ bcA,
                unsigned short* __restrict__ outA,
                unsigned short* __restrict__ outB) {
  __shared__ unsigned short xs[64 * HS];
  const int t = threadIdx.x;

  if (blockIdx.x == 0) {
    int* part = (int*)xs;
    const int lo = t * SCH;
    const int hi = min(lo + SCH, N_PAD);
    int s = 0;
    for (int i = lo; i < hi; ++i) s += deg[i];
    part[t] = s;
    __syncthreads();
    for (int off = 1; off < 256; off <<= 1) {
      int v = (t >= off) ? part[t - off] : 0;
      __syncthreads();
      part[t] += v;
      __syncthreads();
    }
    int run = (t > 0) ? part[t - 1] : 0;
    for (int i = lo; i < hi; ++i) {
      row_ptr[i] = run;
      cursor[i] = run;
      run += deg[i];
    }
    if (t == 255) row_ptr[N_PAD] = part[255];
    return;
  }

  const int r0 = (blockIdx.x - 1) * 64;
  {
    const int e = t >> 2, q = t & 3;
    const int grow = r0 + e;
    const float4* src = (const float4*)(in + (size_t)grow * DF) + q * 8;
#pragma unroll
    for (int i = 0; i < 8; ++i) {
      float4 v = { 0.f, 0.f, 0.f, 0.f };
      if (grow < N_NODES) v = src[i];
      us4 p = { f2bf(v.x), f2bf(v.y), f2bf(v.z), f2bf(v.w) };
      *(us4*)&xs[e * HS + q * 32 + i * 4] = p;
    }
  }
  __syncthreads();

  const int w = t >> 6, l = t & 63, l15 = l & 15, lg = l >> 4;
  f32x4 accA[4][2] = {};
  f32x4 accB[4][2] = {};
  const uint4v* wvA = (const uint4v*)wpA;
  const uint4v* wvB = (const uint4v*)wpB;
#pragma unroll
  for (int kc = 0; kc < 4; ++kc) {
    bf16x8 afr[4];
#pragma unroll
    for (int rt = 0; rt < 4; ++rt)
      afr[rt] = __builtin_bit_cast(bf16x8,
          *(const uint4v*)&xs[(rt * 16 + l15) * HS + kc * 32 + lg * 8]);
#pragma unroll
    for (int c = 0; c < 2; ++c) {
      bf16x8 bfrA = __builtin_bit_cast(bf16x8, wvA[((w * 2 + c) * 4 + kc) * 64 + l]);
      bf16x8 bfrB = __builtin_bit_cast(bf16x8, wvB[((w * 2 + c) * 4 + kc) * 64 + l]);
#pragma unroll
      for (int rt = 0; rt < 4; ++rt) {
        accA[rt][c] = __builtin_amdgcn_mfma_f32_16x16x32_bf16(afr[rt], bfrA, accA[rt][c], 0, 0, 0);
        accB[rt][c] = __builtin_amdgcn_mfma_f32_16x16x32_bf16(afr[rt], bfrB, accB[rt][c], 0, 0, 0);
      }
    }
  }
#pragma unroll
  for (int c = 0; c < 2; ++c) {
    const int col = w * 32 + c * 16 + l15;
    const float cA = bcA[col];
#pragma unroll
    for (int rt = 0; rt < 4; ++rt) {
#pragma unroll
      for (int r = 0; r < 4; ++r) {
        const int grow = r0 + rt * 16 + lg * 4 + r;
        outA[(size_t)grow * DF + col] = f2bf(accA[rt][c][r] + cA);
        outB[(size_t)grow * DF + col] = f2bf(accB[rt][c][r]);
      }
    }
  }
}

// Fused: Hsum1 aggregation (LDS) + combined-weight dual GEMM -> A2, B2 (proven)
__global__ __launch_bounds__(256)
void agg_dual(const unsigned short* __restrict__ A,
              const unsigned short* __restrict__ B,
              const int* __restrict__ row_ptr,
              const int* __restrict__ sorted_src,
              const unsigned short* __restrict__ wpA,
              const unsigned short* __restrict__ wpB,
              const float* __restrict__ bcA, const float* __restrict__ bdA,
              const float* __restrict__ bdB,
              const int* __restrict__ deg,
              unsigned short* __restrict__ outA,
              unsigned short* __restrict__ outB) {
  __shared__ unsigned short xs[64 * HS];
  const int t = threadIdx.x;
  const int r0 = blockIdx.x * 64;

  agg_phase(A, B, row_ptr, sorted_src, xs, r0, t);
  __syncthreads();

  const int w = t >> 6, l = t & 63, l15 = l & 15, lg = l >> 4;
  f32x4 accA[4][2] = {};
  f32x4 accB[4][2] = {};
  const uint4v* wvA = (const uint4v*)wpA;
  const uint4v* wvB = (const uint4v*)wpB;
#pragma unroll
  for (int kc = 0; kc < 4; ++kc) {
    bf16x8 afr[4];
#pragma unroll
    for (int rt = 0; rt < 4; ++rt)
      afr[rt] = __builtin_bit_cast(bf16x8,
          *(const uint4v*)&xs[(rt * 16 + l15) * HS + kc * 32 + lg * 8]);
#pragma unroll
    for (int c = 0; c < 2; ++c) {
      bf16x8 bfrA = __builtin_bit_cast(bf16x8, wvA[((w * 2 + c) * 4 + kc) * 64 + l]);
      bf16x8 bfrB = __builtin_bit_cast(bf16x8, wvB[((w * 2 + c) * 4 + kc) * 64 + l]);
#pragma unroll
      for (int rt = 0; rt < 4; ++rt) {
        accA[rt][c] = __builtin_amdgcn_mfma_f32_16x16x32_bf16(afr[rt], bfrA, accA[rt][c], 0, 0, 0);
        accB[rt][c] = __builtin_amdgcn_mfma_f32_16x16x32_bf16(afr[rt], bfrB, accB[rt][c], 0, 0, 0);
      }
    }
  }
#pragma unroll
  for (int c = 0; c < 2; ++c) {
    const int col = w * 32 + c * 16 + l15;
    const float cA = bcA[col];
    const float dA = bdA[col];
    const float dB = bdB[col];
#pragma unroll
    for (int rt = 0; rt < 4; ++rt) {
#pragma unroll
      for (int r = 0; r < 4; ++r) {
        const int grow = r0 + rt * 16 + lg * 4 + r;
        const float dg = (float)deg[grow];
        outA[(size_t)grow * DF + col] = f2bf(accA[rt][c][r] + cA + dg * dA);
        outB[(size_t)grow * DF + col] = f2bf(accB[rt][c][r] + dg * dB);
      }
    }
  }
}

// Fused layer-2 edge kernel (proven r9).
__global__ __launch_bounds__(256)
void edge_fused2(const unsigned short* __restrict__ A,
                 const unsigned short* __restrict__ B,
                 const int* __restrict__ sorted_src,
                 const int* __restrict__ sorted_dst,
                 const int* __restrict__ sorted_eid,
                 const unsigned short* __restrict__ w2p,
                 const float* __restrict__ b2,
                 float* __restrict__ msg_out,
                 float* __restrict__ Hsum2) {
  __shared__ unsigned short h_s[64 * HS];
  __shared__ int node_s[64];
  __shared__ int eid_s[64];
  const int t = threadIdx.x;
  const int e0 = blockIdx.x * 64;

  {
    const int e = t >> 2, q = t & 3;
    const int pos = e0 + e;
    const int si = sorted_src[pos];
    const int di = sorted_dst[pos];
    if (q == 0) { node_s[e] = di; eid_s[e] = sorted_eid[pos]; }
    const us8* ap = (const us8*)(A + (size_t)di * DF + q * 32);
    const us8* bp = (const us8*)(B + (size_t)si * DF + q * 32);
    us8 av[4], bv[4];
#pragma unroll
    for (int i = 0; i < 4; ++i) { av[i] = ap[i]; bv[i] = bp[i]; }
#pragma unroll
    for (int i = 0; i < 4; ++i) {
      us8 h;
#pragma unroll
      for (int j = 0; j < 8; ++j) {
        float v = bf2f(av[i][j]) + bf2f(bv[i][j]);
        v = v > 0.f ? v : 0.f;
        h[j] = f2bf(v);
      }
      *(us8*)&h_s[e * HS + q * 32 + i * 8] = h;
    }
  }
  __syncthreads();

  const int w = t >> 6, l = t & 63, l15 = l & 15, lg = l >> 4;

  f32x4 acc[4][2] = {};
  const uint4v* wv = (const uint4v*)w2p;
#pragma unroll
  for (int kc = 0; kc < 4; ++kc) {
    bf16x8 afr[4];
#pragma unroll
    for (int rt = 0; rt < 4; ++rt)
      afr[rt] = __builtin_bit_cast(bf16x8,
          *(const uint4v*)&h_s[(rt * 16 + l15) * HS + kc * 32 + lg * 8]);
#pragma unroll
    for (int c = 0; c < 2; ++c) {
      bf16x8 bfr = __builtin_bit_cast(bf16x8, wv[((w * 2 + c) * 4 + kc) * 64 + l]);
#pragma unroll
      for (int rt = 0; rt < 4; ++rt)
        acc[rt][c] = __builtin_amdgcn_mfma_f32_16x16x32_bf16(afr[rt], bfr, acc[rt][c], 0, 0, 0);
    }
  }

  // Hsum2: serial segmented column scan (proven)
  if (t < 128) {
    const int col = t;
    const int prev = (e0 > 0) ? sorted_dst[e0 - 1] : -1;
    const int next = (e0 + 64 < N_EDGES) ? sorted_dst[e0 + 64] : -1;
    int run_n = node_s[0];
    int run_a = 0;
    float racc = 0.f;
    for (int r = 0; r < 64; ++r) {
      const int n = node_s[r];
      if (n != run_n) {
        float* p = &Hsum2[(size_t)run_n * DF + col];
        if (run_a == 0 && prev == run_n) unsafeAtomicAdd(p, racc);
        else *p = racc;
        run_n = n; run_a = r; racc = 0.f;
      }
      racc += bf2f(h_s[r * HS + col]);
    }
    float* p = &Hsum2[(size_t)run_n * DF + col];
    if ((run_a == 0 && prev == run_n) || next == run_n) unsafeAtomicAdd(p, racc);
    else *p = racc;
  }
  __syncthreads();

  // msg tile (bf16) into h_s, then row-coalesced scalar nt scatter
#pragma unroll
  for (int c = 0; c < 2; ++c) {
    const int col = w * 32 + c * 16 + l15;
    const float bv = b2[col];
#pragma unroll
    for (int rt = 0; rt < 4; ++rt) {
#pragma unroll
      for (int r = 0; r < 4; ++r)
        h_s[(rt * 16 + lg * 4 + r) * HS + col] = f2bf(acc[rt][c][r] + bv);
    }
  }
  __syncthreads();

  {
    const int off = (t & 31) * 4;
    const int rbase = t >> 5;
#pragma unroll
    for (int p = 0; p < 8; ++p) {
      const int row = p * 8 + rbase;
      us4 hv = *(const us4*)&h_s[row * HS + off];
      float* dstp = msg_out + (size_t)eid_s[row] * DF + off;
      __builtin_nontemporal_store(bf2f(hv[0]), dstp + 0);
      __builtin_nontemporal_store(bf2f(hv[1]), dstp + 1);
      __builtin_nontemporal_store(bf2f(hv[2]), dstp + 2);
      __builtin_nontemporal_store(bf2f(hv[3]), dstp + 3);
    }
  }
}

// feat2 = Hsum2(fp32) @ W21 + deg*b2_1, scalar nt stores (proven).
__global__ __launch_bounds__(256)
void gemm_out(const float* __restrict__ in,
              const unsigned short* __restrict__ wp,
              const float* __restrict__ bd,
              const int* __restrict__ deg,
              float* __restrict__ out) {
  __shared__ unsigned short xs[64 * HS];
  const int t = threadIdx.x;
  const int r0 = blockIdx.x * 64;
  {
    const int e = t >> 2, q = t & 3;
    const int grow = r0 + e;
    const float4* src = (const float4*)(in + (size_t)grow * DF) + q * 8;
#pragma unroll
    for (int i = 0; i < 8; ++i) {
      float4 v = src[i];
      us4 p = { f2bf(v.x), f2bf(v.y), f2bf(v.z), f2bf(v.w) };
      *(us4*)&xs[e * HS + q * 32 + i * 4] = p;
    }
  }
  __syncthreads();

  const int w = t >> 6, l = t & 63, l15 = l & 15, lg = l >> 4;
  f32x4 acc[4][2] = {};
  const uint4v* wv = (const uint4v*)wp;
#pragma unroll
  for (int kc = 0; kc < 4; ++kc) {
    bf16x8 afr[4];
#pragma unroll
    for (int rt = 0; rt < 4; ++rt)
      afr[rt] = __builtin_bit_cast(bf16x8,
          *(const uint4v*)&xs[(rt * 16 + l15) * HS + kc * 32 + lg * 8]);
#pragma unroll
    for (int c = 0; c < 2; ++c) {
      bf16x8 bfr = __builtin_bit_cast(bf16x8, wv[((w * 2 + c) * 4 + kc) * 64 + l]);
#pragma unroll
      for (int rt = 0; rt < 4; ++rt)
        acc[rt][c] = __builtin_amdgcn_mfma_f32_16x16x32_bf16(afr[rt], bfr, acc[rt][c], 0, 0, 0);
    }
  }
#pragma unroll
  for (int c = 0; c < 2; ++c) {
    const int col = w * 32 + c * 16 + l15;
    const float bv = bd[col];
#pragma unroll
    for (int rt = 0; rt < 4; ++rt) {
#pragma unroll
      for (int r = 0; r < 4; ++r) {
        const int grow = r0 + rt * 16 + lg * 4 + r;
        if (grow < N_NODES) {
          const float v = acc[rt][c][r] + (float)deg[grow] * bv;
          __builtin_nontemporal_store(v, &out[(size_t)grow * DF + col]);
        }
      }
    }
  }
}

extern "C" void kernel_launch(void* const* d_in, const int* in_sizes, int n_in,
                              void* d_out, int out_size, void* d_ws, size_t ws_size,
                              hipStream_t stream) {
  const float* x    = (const float*)d_in[0];
  const int*   eidx = (const int*)d_in[1];
  const float* W1_0 = (const float*)d_in[2];
  const float* b1_0 = (const float*)d_in[3];
  const float* W2_0 = (const float*)d_in[4];
  const float* b2_0 = (const float*)d_in[5];
  const float* W1_1 = (const float*)d_in[6];
  const float* b1_1 = (const float*)d_in[7];
  const float* W2_1 = (const float*)d_in[8];
  const float* b2_1 = (const float*)d_in[9];

  const int* src = eidx;
  const int* dst = eidx + N_EDGES;

  float* feat2 = (float*)d_out;
  float* msg2  = feat2 + (size_t)N_NODES * DF;

  // ---- workspace layout (~62 MB; Hsum2 aliases A1/B1, dead after agg_dual) ----
  char* ws = (char*)d_ws;
  const size_t BF_ROWS = (size_t)N_PAD * DF;
  unsigned short* A1 = (unsigned short*)ws;  ws += BF_ROWS * 2;   // 12.8 MB
  unsigned short* B1 = (unsigned short*)ws;  ws += BF_ROWS * 2;   // 12.8 MB
  unsigned short* A2 = (unsigned short*)ws;  ws += BF_ROWS * 2;   // 12.8 MB
  unsigned short* B2 = (unsigned short*)ws;  ws += BF_ROWS * 2;   // 12.8 MB
  float* Hsum2 = (float*)A1;                 // 25.6 MB alias over A1+B1
  int* deg        = (int*)ws;  ws += (size_t)N_PAD * 4;
  int* row_ptr    = (int*)ws;  ws += (size_t)(N_PAD + 1) * 4;
  int* cursor     = (int*)ws;  ws += (size_t)N_PAD * 4;
  int* sorted_src = (int*)ws;  ws += (size_t)N_EDGES * 4;         // 3.2 MB
  int* sorted_dst = (int*)ws;  ws += (size_t)N_EDGES * 4;         // 3.2 MB
  int* sorted_eid = (int*)ws;  ws += (size_t)N_EDGES * 4;         // 3.2 MB
  float* vA     = (float*)ws;  ws += 128 * 4;
  float* vB     = (float*)ws;  ws += 128 * 4;
  unsigned short* wa1p  = (unsigned short*)ws;  ws += 16384 * 2;
  unsigned short* wb1p  = (unsigned short*)ws;  ws += 16384 * 2;
  unsigned short* w21p  = (unsigned short*)ws;  ws += 16384 * 2;
  unsigned short* w20Ap = (unsigned short*)ws;  ws += 16384 * 2;
  unsigned short* w20Bp = (unsigned short*)ws;  ws += 16384 * 2;

  hipMemsetAsync(deg, 0, (size_t)N_PAD * 4, stream);

  // Fused weight prep (wcomb direct-packed + 3 packs) + deg histogram.
  wprep_deg<<<153 + DEG_BLOCKS, 256, 0, stream>>>(
      W2_0, W1_1, b2_0, W1_0, W2_1,
      w20Ap, w20Bp, vA, vB, wa1p, wb1p, w21p, dst, deg);

  // Fat: scan (block 0) + layer-1 dual GEMM (blocks 1..NG).
  scan_gemm1<<<1 + NG, 256, 0, stream>>>(deg, row_ptr, cursor,
                                         x, wa1p, wb1p, b1_0, A1, B1);

  sort_kernel<<<DEG_BLOCKS, 256, 0, stream>>>(src, dst, cursor,
                                              sorted_src, sorted_dst, sorted_eid);

  // Fused aggregate(Hsum1) + combined-weight dual GEMM -> A2, B2
  agg_dual<<<NG, 256, 0, stream>>>(A1, B1, row_ptr, sorted_src,
                                   w20Ap, w20Bp, b1_1, vA, vB, deg, A2, B2);

  // A1/B1 now dead -> zero the aliased Hsum2 region (stream-ordered)
  hipMemsetAsync(Hsum2, 0, BF_ROWS * 4, stream);

  // Fused: msg2 (LDS-bounce coalesced nt scatter) + Hsum2 (serial segment scan)
  edge_fused2<<<N_EDGES / 64, 256, 0, stream>>>(A2, B2, sorted_src, sorted_dst,
                                                sorted_eid, w21p, b2_1, msg2, Hsum2);

  // feat2 = Hsum2@W21 + deg*b2_1  (no gather)
  gemm_out<<<NG, 256, 0, stream>>>(Hsum2, w21p, b2_1, deg, feat2);
}

// Round 11
// 425.175 us; speedup vs baseline: 1.2699x; 1.1034x over previous
//
#include <hip/hip_runtime.h>
#include <hip/hip_bf16.h>

#define N_NODES 50000
#define N_PAD   50048      // 64-row multiple for guard-free GEMM tiles
#define N_EDGES 800000
#define DF 128
#define NG (N_PAD / 64)    // 782 node-GEMM blocks
#define DEG_BLOCKS (N_EDGES / 256)  // 3125

// LDS row stride (ushorts): 128 bf16 + 8 pad (272 B = 17*16 B)
#define HS 136

typedef __bf16 bf16x8 __attribute__((ext_vector_type(8)));
typedef float f32x4 __attribute__((ext_vector_type(4)));
typedef unsigned int uint4v __attribute__((ext_vector_type(4)));
typedef unsigned short us4 __attribute__((ext_vector_type(4)));
typedef unsigned short us8 __attribute__((ext_vector_type(8)));

__device__ __forceinline__ unsigned short f2bf(float f) {
  unsigned u = __builtin_bit_cast(unsigned, f);
  u += 0x7FFFu + ((u >> 16) & 1u);   // RNE
  return (unsigned short)(u >> 16);
}
__device__ __forceinline__ float bf2f(unsigned short u) {
  return __builtin_bit_cast(float, ((unsigned)u) << 16);
}

// Packed-fragment offset for element (k,col) of a [128][128] matrix.
__device__ __forceinline__ int pack_off(int k, int c) {
  return ((((c >> 4) * 4 + (k >> 5)) * 64) + ((k >> 3) & 3) * 16 + (c & 15)) * 8
         + (k & 7);
}

// ---------------- fused weight prep + deg histogram (proven r10) ----------------
__global__ __launch_bounds__(256)
void wprep_deg(const float* __restrict__ W2_0,
               const float* __restrict__ W1_1,
               const float* __restrict__ b2_0,
               const float* __restrict__ W1_0,
               const float* __restrict__ W2_1,
               unsigned short* __restrict__ w20Ap,
               unsigned short* __restrict__ w20Bp,
               float* __restrict__ vA,
               float* __restrict__ vB,
               unsigned short* __restrict__ wa1p,
               unsigned short* __restrict__ wb1p,
               unsigned short* __restrict__ w21p,
               const int* __restrict__ dst,
               int* __restrict__ deg) {
  const int b = blockIdx.x;
  const int t = threadIdx.x;

  if (b < 129) {                      // wcomb, direct-packed
    const int c = t & 127;
    const bool isB = t >= 128;
    float acc = 0.f;
    if (b < 128) {
      const float* wrow = W2_0 + (size_t)b * DF;
      for (int k = 0; k < 128; ++k) {
        float bot = W1_1[(size_t)(128 + k) * DF + c];
        float w = isB ? bot : (W1_1[(size_t)k * DF + c] - bot);
        acc += wrow[k] * w;
      }
      unsigned short* out = isB ? w20Bp : w20Ap;
      out[pack_off(b, c)] = f2bf(acc);
    } else {
      for (int k = 0; k < 128; ++k) {
        float bot = W1_1[(size_t)(128 + k) * DF + c];
        float w = isB ? bot : (W1_1[(size_t)k * DF + c] - bot);
        acc += b2_0[k] * w;
      }
      if (isB) vB[c] = acc;
      else     vA[c] = acc;
    }
    return;
  }

  if (b < 153) {                      // pack wa1p / wb1p / w21p
    const int mat = (b - 129) >> 3;
    const int idx = ((b - 129) & 7) * 256 + t;   // < 2048
    const int l = idx & 63;
    const int blk = idx >> 6;
    const int ct = blk >> 2;
    const int kc = blk & 3;
    const int col = ct * 16 + (l & 15);
    const int k0 = kc * 32 + (l >> 4) * 8;
    const float* W;
    const float* Wsub = nullptr;
    unsigned short* out;
    if (mat == 0)      { W = W1_0;            Wsub = W1_0 + 128 * DF; out = wa1p; }
    else if (mat == 1) { W = W1_0 + 128 * DF;                         out = wb1p; }
    else               { W = W2_1;                                    out = w21p; }
    unsigned short tmp[8];
#pragma unroll
    for (int j = 0; j < 8; ++j) {
      float v = W[(size_t)(k0 + j) * DF + col];
      if (Wsub) v -= Wsub[(size_t)(k0 + j) * DF + col];
      tmp[j] = f2bf(v);
    }
    us4 lo = { tmp[0], tmp[1], tmp[2], tmp[3] };
    us4 hi = { tmp[4], tmp[5], tmp[6], tmp[7] };
    us4* o = (us4*)(out + (size_t)idx * 8);
    o[0] = lo;
    o[1] = hi;
    return;
  }

  // deg histogram
  const int e = (b - 153) * 256 + t;
  if (e < N_EDGES) atomicAdd(&deg[dst[e]], 1);
}

// ---------------- CSR sort (proven) ----------------
__global__ void sort_kernel(const int* __restrict__ src,
                            const int* __restrict__ dst,
                            int* __restrict__ cursor,
                            int* __restrict__ sorted_src,
                            int* __restrict__ sorted_dst,
                            int* __restrict__ sorted_eid) {
  const int e = blockIdx.x * 256 + threadIdx.x;
  const int d = dst[e];
  const int pos = atomicAdd(&cursor[d], 1);
  sorted_src[pos] = src[e];
  sorted_dst[pos] = d;
  sorted_eid[pos] = e;
}

// ---------------- shared device pieces (proven r6/r9) ----------------
__device__ __forceinline__ void agg_phase(const unsigned short* __restrict__ A,
                                          const unsigned short* __restrict__ B,
                                          const int* __restrict__ row_ptr,
                                          const int* __restrict__ sorted_src,
                                          unsigned short* xs, int r0, int t) {
  const int w = t >> 6, l = t & 63;
  const int lane16 = l & 15;
  const int g = l >> 4;
#pragma unroll
  for (int i = 0; i < 4; ++i) {
    const int nl = w * 16 + i * 4 + g;       // 0..63
    const int n = r0 + nl;
    const int beg = row_ptr[n];
    const int end = row_ptr[n + 1];
    us8 av = *(const us8*)(A + (size_t)n * DF + lane16 * 8);
    float af[8];
#pragma unroll
    for (int j = 0; j < 8; ++j) af[j] = bf2f(av[j]);
    float acc[8] = {};
    int k = beg;
    for (; k + 4 <= end; k += 4) {
      const int s0 = sorted_src[k + 0];
      const int s1 = sorted_src[k + 1];
      const int s2 = sorted_src[k + 2];
      const int s3 = sorted_src[k + 3];
      us8 b0 = *(const us8*)(B + (size_t)s0 * DF + lane16 * 8);
      us8 b1 = *(const us8*)(B + (size_t)s1 * DF + lane16 * 8);
      us8 b2 = *(const us8*)(B + (size_t)s2 * DF + lane16 * 8);
      us8 b3 = *(const us8*)(B + (size_t)s3 * DF + lane16 * 8);
#pragma unroll
      for (int j = 0; j < 8; ++j) {
        float v0 = af[j] + bf2f(b0[j]);
        float v1 = af[j] + bf2f(b1[j]);
        float v2 = af[j] + bf2f(b2[j]);
        float v3 = af[j] + bf2f(b3[j]);
        acc[j] += (v0 > 0.f ? v0 : 0.f) + (v1 > 0.f ? v1 : 0.f)
                + (v2 > 0.f ? v2 : 0.f) + (v3 > 0.f ? v3 : 0.f);
      }
    }
    for (; k < end; ++k) {
      const int s = sorted_src[k];
      us8 bv = *(const us8*)(B + (size_t)s * DF + lane16 * 8);
#pragma unroll
      for (int j = 0; j < 8; ++j) {
        float v = af[j] + bf2f(bv[j]);
        acc[j] += v > 0.f ? v : 0.f;
      }
    }
    us8 o;
#pragma unroll
    for (int j = 0; j < 8; ++j) o[j] = f2bf(acc[j]);
    *(us8*)&xs[nl * HS + lane16 * 8] = o;
  }
}

// ---------------- kernels ----------------

// Fat kernel: block 0 = scan; blocks 1..NG = layer-1 dual GEMM (proven r10).
#define SCH ((N_PAD + 255) / 256)   // 196
__global__ __launch_bounds__(256)
void scan_gemm1(const int* __restrict__ deg,
                int* __restrict__ row_ptr,
                int* __restrict__ cursor,
                const float* __restrict__ in,
                const unsigned short* __restrict__ wpA,
                const unsigned short* __restrict__ wpB,
                const float* __restrict__ bcA,
                unsigned short* __restrict__ outA,
                unsigned short* __restrict__ outB) {
  __shared__ unsigned short xs[64 * HS];
  const int t = threadIdx.x;

  if (blockIdx.x == 0) {
    int* part = (int*)xs;
    const int lo = t * SCH;
    const int hi = min(lo + SCH, N_PAD);
    int s = 0;
    for (int i = lo; i < hi; ++i) s += deg[i];
    part[t] = s;
    __syncthreads();
    for (int off = 1; off < 256; off <<= 1) {
      int v = (t >= off) ? part[t - off] : 0;
      __syncthreads();
      part[t] += v;
      __syncthreads();
    }
    int run = (t > 0) ? part[t - 1] : 0;
    for (int i = lo; i < hi; ++i) {
      row_ptr[i] = run;
      cursor[i] = run;
      run += deg[i];
    }
    if (t == 255) row_ptr[N_PAD] = part[255];
    return;
  }

  const int r0 = (blockIdx.x - 1) * 64;
  {
    const int e = t >> 2, q = t & 3;
    const int grow = r0 + e;
    const float4* src = (const float4*)(in + (size_t)grow * DF) + q * 8;
#pragma unroll
    for (int i = 0; i < 8; ++i) {
      float4 v = { 0.f, 0.f, 0.f, 0.f };
      if (grow < N_NODES) v = src[i];
      us4 p = { f2bf(v.x), f2bf(v.y), f2bf(v.z), f2bf(v.w) };
      *(us4*)&xs[e * HS + q * 32 + i * 4] = p;
    }
  }
  __syncthreads();

  const int w = t >> 6, l = t & 63, l15 = l & 15, lg = l >> 4;
  f32x4 accA[4][2] = {};
  f32x4 accB[4][2] = {};
  const uint4v* wvA = (const uint4v*)wpA;
  const uint4v* wvB = (const uint4v*)wpB;
#pragma unroll
  for (int kc = 0; kc < 4; ++kc) {
    bf16x8 afr[4];
#pragma unroll
    for (int rt = 0; rt < 4; ++rt)
      afr[rt] = __builtin_bit_cast(bf16x8,
          *(const uint4v*)&xs[(rt * 16 + l15) * HS + kc * 32 + lg * 8]);
#pragma unroll
    for (int c = 0; c < 2; ++c) {
      bf16x8 bfrA = __builtin_bit_cast(bf16x8, wvA[((w * 2 + c) * 4 + kc) * 64 + l]);
      bf16x8 bfrB = __builtin_bit_cast(bf16x8, wvB[((w * 2 + c) * 4 + kc) * 64 + l]);
#pragma unroll
      for (int rt = 0; rt < 4; ++rt) {
        accA[rt][c] = __builtin_amdgcn_mfma_f32_16x16x32_bf16(afr[rt], bfrA, accA[rt][c], 0, 0, 0);
        accB[rt][c] = __builtin_amdgcn_mfma_f32_16x16x32_bf16(afr[rt], bfrB, accB[rt][c], 0, 0, 0);
      }
    }
  }
#pragma unroll
  for (int c = 0; c < 2; ++c) {
    const int col = w * 32 + c * 16 + l15;
    const float cA = bcA[col];
#pragma unroll
    for (int rt = 0; rt < 4; ++rt) {
#pragma unroll
      for (int r = 0; r < 4; ++r) {
        const int grow = r0 + rt * 16 + lg * 4 + r;
        outA[(size_t)grow * DF + col] = f2bf(accA[rt][c][r] + cA);
        outB[(size_t)grow * DF + col] = f2bf(accB[rt][c][r]);
      }
    }
  }
}

// Fused: Hsum1 aggregation (LDS) + combined-weight dual GEMM -> A2, B2 (proven)
__global__ __launch_bounds__(256)
void agg_dual(const unsigned short* __restrict__ A,
              const unsigned short* __restrict__ B,
              const int* __restrict__ row_ptr,
              const int* __restrict__ sorted_src,
              const unsigned short* __restrict__ wpA,
              const unsigned short* __restrict__ wpB,
              const float* __restrict__ bcA, const float* __restrict__ bdA,
              const float* __restrict__ bdB,
              const int* __restrict__ deg,
              unsigned short* __restrict__ outA,
              unsigned short* __restrict__ outB) {
  __shared__ unsigned short xs[64 * HS];
  const int t = threadIdx.x;
  const int r0 = blockIdx.x * 64;

  agg_phase(A, B, row_ptr, sorted_src, xs, r0, t);
  __syncthreads();

  const int w = t >> 6, l = t & 63, l15 = l & 15, lg = l >> 4;
  f32x4 accA[4][2] = {};
  f32x4 accB[4][2] = {};
  const uint4v* wvA = (const uint4v*)wpA;
  const uint4v* wvB = (const uint4v*)wpB;
#pragma unroll
  for (int kc = 0; kc < 4; ++kc) {
    bf16x8 afr[4];
#pragma unroll
    for (int rt = 0; rt < 4; ++rt)
      afr[rt] = __builtin_bit_cast(bf16x8,
          *(const uint4v*)&xs[(rt * 16 + l15) * HS + kc * 32 + lg * 8]);
#pragma unroll
    for (int c = 0; c < 2; ++c) {
      bf16x8 bfrA = __builtin_bit_cast(bf16x8, wvA[((w * 2 + c) * 4 + kc) * 64 + l]);
      bf16x8 bfrB = __builtin_bit_cast(bf16x8, wvB[((w * 2 + c) * 4 + kc) * 64 + l]);
#pragma unroll
      for (int rt = 0; rt < 4; ++rt) {
        accA[rt][c] = __builtin_amdgcn_mfma_f32_16x16x32_bf16(afr[rt], bfrA, accA[rt][c], 0, 0, 0);
        accB[rt][c] = __builtin_amdgcn_mfma_f32_16x16x32_bf16(afr[rt], bfrB, accB[rt][c], 0, 0, 0);
      }
    }
  }
#pragma unroll
  for (int c = 0; c < 2; ++c) {
    const int col = w * 32 + c * 16 + l15;
    const float cA = bcA[col];
    const float dA = bdA[col];
    const float dB = bdB[col];
#pragma unroll
    for (int rt = 0; rt < 4; ++rt) {
#pragma unroll
      for (int r = 0; r < 4; ++r) {
        const int grow = r0 + rt * 16 + lg * 4 + r;
        const float dg = (float)deg[grow];
        outA[(size_t)grow * DF + col] = f2bf(accA[rt][c][r] + cA + dg * dA);
        outB[(size_t)grow * DF + col] = f2bf(accB[rt][c][r] + dg * dB);
      }
    }
  }
}

// Fused layer-2 edge kernel: h = relu(A2[dst]+B2[src]); msg = h@W21 + b2_1.
// msg tile (bf16) -> LDS; scatter msg rows (orig eid, coalesced nt); segment-
// sum the BIASED msg tile directly into feat2 (plain interior / atomic
// boundary onto zeroed feat2). Since each msg row includes +b2_1, the segment
// sum equals Hsum2@W21 + deg*b2_1 — gemm_out eliminated.
__global__ __launch_bounds__(256)
void edge_fused3(const unsigned short* __restrict__ A,
                 const unsigned short* __restrict__ B,
                 const int* __restrict__ sorted_src,
                 const int* __restrict__ sorted_dst,
                 const int* __restrict__ sorted_eid,
                 const unsigned short* __restrict__ w2p,
                 const float* __restrict__ b2,
                 float* __restrict__ msg_out,
                 float* __restrict__ feat_out) {
  __shared__ unsigned short h_s[64 * HS];
  __shared__ int node_s[64];
  __shared__ int eid_s[64];
  const int t = threadIdx.x;
  const int e0 = blockIdx.x * 64;

  // ---- stage h (proven)
  {
    const int e = t >> 2, q = t & 3;
    const int pos = e0 + e;
    const int si = sorted_src[pos];
    const int di = sorted_dst[pos];
    if (q == 0) { node_s[e] = di; eid_s[e] = sorted_eid[pos]; }
    const us8* ap = (const us8*)(A + (size_t)di * DF + q * 32);
    const us8* bp = (const us8*)(B + (size_t)si * DF + q * 32);
    us8 av[4], bv[4];
#pragma unroll
    for (int i = 0; i < 4; ++i) { av[i] = ap[i]; bv[i] = bp[i]; }
#pragma unroll
    for (int i = 0; i < 4; ++i) {
      us8 h;
#pragma unroll
      for (int j = 0; j < 8; ++j) {
        float v = bf2f(av[i][j]) + bf2f(bv[i][j]);
        v = v > 0.f ? v : 0.f;
        h[j] = f2bf(v);
      }
      *(us8*)&h_s[e * HS + q * 32 + i * 8] = h;
    }
  }
  __syncthreads();

  const int w = t >> 6, l = t & 63, l15 = l & 15, lg = l >> 4;

  // ---- GEMM: msg = h @ W21 (proven)
  f32x4 acc[4][2] = {};
  const uint4v* wv = (const uint4v*)w2p;
#pragma unroll
  for (int kc = 0; kc < 4; ++kc) {
    bf16x8 afr[4];
#pragma unroll
    for (int rt = 0; rt < 4; ++rt)
      afr[rt] = __builtin_bit_cast(bf16x8,
          *(const uint4v*)&h_s[(rt * 16 + l15) * HS + kc * 32 + lg * 8]);
#pragma unroll
    for (int c = 0; c < 2; ++c) {
      bf16x8 bfr = __builtin_bit_cast(bf16x8, wv[((w * 2 + c) * 4 + kc) * 64 + l]);
#pragma unroll
      for (int rt = 0; rt < 4; ++rt)
        acc[rt][c] = __builtin_amdgcn_mfma_f32_16x16x32_bf16(afr[rt], bfr, acc[rt][c], 0, 0, 0);
    }
  }
  __syncthreads();   // all GEMM reads of h_s done before overwrite

  // ---- overwrite h_s with biased msg tile (bf16)
#pragma unroll
  for (int c = 0; c < 2; ++c) {
    const int col = w * 32 + c * 16 + l15;
    const float bv = b2[col];
#pragma unroll
    for (int rt = 0; rt < 4; ++rt) {
#pragma unroll
      for (int r = 0; r < 4; ++r)
        h_s[(rt * 16 + lg * 4 + r) * HS + col] = f2bf(acc[rt][c][r] + bv);
    }
  }
  __syncthreads();

  // ---- scatter msg rows (orig eid, row-coalesced scalar nt)
  {
    const int off = (t & 31) * 4;
    const int rbase = t >> 5;
#pragma unroll
    for (int p = 0; p < 8; ++p) {
      const int row = p * 8 + rbase;
      us4 hv = *(const us4*)&h_s[row * HS + off];
      float* dstp = msg_out + (size_t)eid_s[row] * DF + off;
      __builtin_nontemporal_store(bf2f(hv[0]), dstp + 0);
      __builtin_nontemporal_store(bf2f(hv[1]), dstp + 1);
      __builtin_nontemporal_store(bf2f(hv[2]), dstp + 2);
      __builtin_nontemporal_store(bf2f(hv[3]), dstp + 3);
    }
  }

  // ---- feat2: serial segmented column scan over the msg tile (proven scheme)
  if (t < 128) {
    const int col = t;
    const int prev = (e0 > 0) ? sorted_dst[e0 - 1] : -1;
    const int next = (e0 + 64 < N_EDGES) ? sorted_dst[e0 + 64] : -1;
    int run_n = node_s[0];
    int run_a = 0;
    float racc = 0.f;
    for (int r = 0; r < 64; ++r) {
      const int n = node_s[r];
      if (n != run_n) {
        float* p = &feat_out[(size_t)run_n * DF + col];
        if (run_a == 0 && prev == run_n) unsafeAtomicAdd(p, racc);
        else *p = racc;
        run_n = n; run_a = r; racc = 0.f;
      }
      racc += bf2f(h_s[r * HS + col]);
    }
    float* p = &feat_out[(size_t)run_n * DF + col];
    if ((run_a == 0 && prev == run_n) || next == run_n) unsafeAtomicAdd(p, racc);
    else *p = racc;
  }
}

extern "C" void kernel_launch(void* const* d_in, const int* in_sizes, int n_in,
                              void* d_out, int out_size, void* d_ws, size_t ws_size,
                              hipStream_t stream) {
  const float* x    = (const float*)d_in[0];
  const int*   eidx = (const int*)d_in[1];
  const float* W1_0 = (const float*)d_in[2];
  const float* b1_0 = (const float*)d_in[3];
  const float* W2_0 = (const float*)d_in[4];
  const float* b2_0 = (const float*)d_in[5];
  const float* W1_1 = (const float*)d_in[6];
  const float* b1_1 = (const float*)d_in[7];
  const float* W2_1 = (const float*)d_in[8];
  const float* b2_1 = (const float*)d_in[9];

  const int* src = eidx;
  const int* dst = eidx + N_EDGES;

  float* feat2 = (float*)d_out;
  float* msg2  = feat2 + (size_t)N_NODES * DF;

  // ---- workspace layout (~62 MB) ----
  char* ws = (char*)d_ws;
  const size_t BF_ROWS = (size_t)N_PAD * DF;
  unsigned short* A1 = (unsigned short*)ws;  ws += BF_ROWS * 2;   // 12.8 MB
  unsigned short* B1 = (unsigned short*)ws;  ws += BF_ROWS * 2;   // 12.8 MB
  unsigned short* A2 = (unsigned short*)ws;  ws += BF_ROWS * 2;   // 12.8 MB
  unsigned short* B2 = (unsigned short*)ws;  ws += BF_ROWS * 2;   // 12.8 MB
  int* deg        = (int*)ws;  ws += (size_t)N_PAD * 4;
  int* row_ptr    = (int*)ws;  ws += (size_t)(N_PAD + 1) * 4;
  int* cursor     = (int*)ws;  ws += (size_t)N_PAD * 4;
  int* sorted_src = (int*)ws;  ws += (size_t)N_EDGES * 4;         // 3.2 MB
  int* sorted_dst = (int*)ws;  ws += (size_t)N_EDGES * 4;         // 3.2 MB
  int* sorted_eid = (int*)ws;  ws += (size_t)N_EDGES * 4;         // 3.2 MB
  float* vA     = (float*)ws;  ws += 128 * 4;
  float* vB     = (float*)ws;  ws += 128 * 4;
  unsigned short* wa1p  = (unsigned short*)ws;  ws += 16384 * 2;
  unsigned short* wb1p  = (unsigned short*)ws;  ws += 16384 * 2;
  unsigned short* w21p  = (unsigned short*)ws;  ws += 16384 * 2;
  unsigned short* w20Ap = (unsigned short*)ws;  ws += 16384 * 2;
  unsigned short* w20Bp = (unsigned short*)ws;  ws += 16384 * 2;

  hipMemsetAsync(deg, 0, (size_t)N_PAD * 4, stream);
  // feat2 zero-init: boundary segments atomicAdd onto it; deg-0 nodes stay 0.
  hipMemsetAsync(feat2, 0, (size_t)N_NODES * DF * 4, stream);

  // Fused weight prep (wcomb direct-packed + 3 packs) + deg histogram.
  wprep_deg<<<153 + DEG_BLOCKS, 256, 0, stream>>>(
      W2_0, W1_1, b2_0, W1_0, W2_1,
      w20Ap, w20Bp, vA, vB, wa1p, wb1p, w21p, dst, deg);

  // Fat: scan (block 0) + layer-1 dual GEMM (blocks 1..NG).
  scan_gemm1<<<1 + NG, 256, 0, stream>>>(deg, row_ptr, cursor,
                                         x, wa1p, wb1p, b1_0, A1, B1);

  sort_kernel<<<DEG_BLOCKS, 256, 0, stream>>>(src, dst, cursor,
                                              sorted_src, sorted_dst, sorted_eid);

  // Fused aggregate(Hsum1) + combined-weight dual GEMM -> A2, B2
  agg_dual<<<NG, 256, 0, stream>>>(A1, B1, row_ptr, sorted_src,
                                   w20Ap, w20Bp, b1_1, vA, vB, deg, A2, B2);

  // Fused: msg2 (LDS-bounce coalesced nt scatter) + feat2 (segment-sum of msg)
  edge_fused3<<<N_EDGES / 64, 256, 0, stream>>>(A2, B2, sorted_src, sorted_dst,
                                                sorted_eid, w21p, b2_1, msg2, feat2);
}

// Round 12
// 422.104 us; speedup vs baseline: 1.2791x; 1.0073x over previous
//
#include <hip/hip_runtime.h>
#include <hip/hip_bf16.h>

#define N_NODES 50000
#define N_PAD   50048      // 64-row multiple for guard-free GEMM tiles
#define N_EDGES 800000
#define DF 128
#define NG (N_PAD / 64)    // 782 node-GEMM blocks
#define DEG_BLOCKS (N_EDGES / 256)  // 3125

// LDS row stride (ushorts): 128 bf16 + 8 pad (272 B = 17*16 B)
#define HS 136

typedef __bf16 bf16x8 __attribute__((ext_vector_type(8)));
typedef float f32x4 __attribute__((ext_vector_type(4)));
typedef unsigned int uint4v __attribute__((ext_vector_type(4)));
typedef unsigned short us4 __attribute__((ext_vector_type(4)));
typedef unsigned short us8 __attribute__((ext_vector_type(8)));

__device__ __forceinline__ unsigned short f2bf(float f) {
  unsigned u = __builtin_bit_cast(unsigned, f);
  u += 0x7FFFu + ((u >> 16) & 1u);   // RNE
  return (unsigned short)(u >> 16);
}
__device__ __forceinline__ float bf2f(unsigned short u) {
  return __builtin_bit_cast(float, ((unsigned)u) << 16);
}

// Packed-fragment offset for element (k,col) of a [128][128] matrix.
__device__ __forceinline__ int pack_off(int k, int c) {
  return ((((c >> 4) * 4 + (k >> 5)) * 64) + ((k >> 3) & 3) * 16 + (c & 15)) * 8
         + (k & 7);
}

// ---------------- fused weight prep + deg histogram (proven r10) ----------------
__global__ __launch_bounds__(256)
void wprep_deg(const float* __restrict__ W2_0,
               const float* __restrict__ W1_1,
               const float* __restrict__ b2_0,
               const float* __restrict__ W1_0,
               const float* __restrict__ W2_1,
               unsigned short* __restrict__ w20Ap,
               unsigned short* __restrict__ w20Bp,
               float* __restrict__ vA,
               float* __restrict__ vB,
               unsigned short* __restrict__ wa1p,
               unsigned short* __restrict__ wb1p,
               unsigned short* __restrict__ w21p,
               const int* __restrict__ dst,
               int* __restrict__ deg) {
  const int b = blockIdx.x;
  const int t = threadIdx.x;

  if (b < 129) {                      // wcomb, direct-packed
    const int c = t & 127;
    const bool isB = t >= 128;
    float acc = 0.f;
    if (b < 128) {
      const float* wrow = W2_0 + (size_t)b * DF;
      for (int k = 0; k < 128; ++k) {
        float bot = W1_1[(size_t)(128 + k) * DF + c];
        float w = isB ? bot : (W1_1[(size_t)k * DF + c] - bot);
        acc += wrow[k] * w;
      }
      unsigned short* out = isB ? w20Bp : w20Ap;
      out[pack_off(b, c)] = f2bf(acc);
    } else {
      for (int k = 0; k < 128; ++k) {
        float bot = W1_1[(size_t)(128 + k) * DF + c];
        float w = isB ? bot : (W1_1[(size_t)k * DF + c] - bot);
        acc += b2_0[k] * w;
      }
      if (isB) vB[c] = acc;
      else     vA[c] = acc;
    }
    return;
  }

  if (b < 153) {                      // pack wa1p / wb1p / w21p
    const int mat = (b - 129) >> 3;
    const int idx = ((b - 129) & 7) * 256 + t;   // < 2048
    const int l = idx & 63;
    const int blk = idx >> 6;
    const int ct = blk >> 2;
    const int kc = blk & 3;
    const int col = ct * 16 + (l & 15);
    const int k0 = kc * 32 + (l >> 4) * 8;
    const float* W;
    const float* Wsub = nullptr;
    unsigned short* out;
    if (mat == 0)      { W = W1_0;            Wsub = W1_0 + 128 * DF; out = wa1p; }
    else if (mat == 1) { W = W1_0 + 128 * DF;                         out = wb1p; }
    else               { W = W2_1;                                    out = w21p; }
    unsigned short tmp[8];
#pragma unroll
    for (int j = 0; j < 8; ++j) {
      float v = W[(size_t)(k0 + j) * DF + col];
      if (Wsub) v -= Wsub[(size_t)(k0 + j) * DF + col];
      tmp[j] = f2bf(v);
    }
    us4 lo = { tmp[0], tmp[1], tmp[2], tmp[3] };
    us4 hi = { tmp[4], tmp[5], tmp[6], tmp[7] };
    us4* o = (us4*)(out + (size_t)idx * 8);
    o[0] = lo;
    o[1] = hi;
    return;
  }

  // deg histogram
  const int e = (b - 153) * 256 + t;
  if (e < N_EDGES) atomicAdd(&deg[dst[e]], 1);
}

// ---------------- CSR sort: packed (src,eid) + dst ----------------
__global__ void sort_kernel(const int* __restrict__ src,
                            const int* __restrict__ dst,
                            int* __restrict__ cursor,
                            int2* __restrict__ sorted_se,
                            int* __restrict__ sorted_dst) {
  const int e = blockIdx.x * 256 + threadIdx.x;
  const int d = dst[e];
  const int pos = atomicAdd(&cursor[d], 1);
  sorted_se[pos] = make_int2(src[e], e);
  sorted_dst[pos] = d;
}

// ---------------- shared device pieces ----------------
// Layer-1 aggregation into LDS (GEMM staging layout), 8-deep gather batching.
__device__ __forceinline__ void agg_phase(const unsigned short* __restrict__ A,
                                          const unsigned short* __restrict__ B,
                                          const int* __restrict__ row_ptr,
                                          const int2* __restrict__ sorted_se,
                                          unsigned short* xs, int r0, int t) {
  const int w = t >> 6, l = t & 63;
  const int lane16 = l & 15;
  const int g = l >> 4;
#pragma unroll
  for (int i = 0; i < 4; ++i) {
    const int nl = w * 16 + i * 4 + g;       // 0..63
    const int n = r0 + nl;
    const int beg = row_ptr[n];
    const int end = row_ptr[n + 1];
    us8 av = *(const us8*)(A + (size_t)n * DF + lane16 * 8);
    float af[8];
#pragma unroll
    for (int j = 0; j < 8; ++j) af[j] = bf2f(av[j]);
    float acc[8] = {};
    int k = beg;
    for (; k + 8 <= end; k += 8) {
      us8 bv[8];
#pragma unroll
      for (int u = 0; u < 8; ++u) {
        const int s = sorted_se[k + u].x;
        bv[u] = *(const us8*)(B + (size_t)s * DF + lane16 * 8);
      }
#pragma unroll
      for (int j = 0; j < 8; ++j) {
#pragma unroll
        for (int u = 0; u < 8; ++u) {
          float v = af[j] + bf2f(bv[u][j]);
          acc[j] += v > 0.f ? v : 0.f;
        }
      }
    }
    for (; k < end; ++k) {
      const int s = sorted_se[k].x;
      us8 bv = *(const us8*)(B + (size_t)s * DF + lane16 * 8);
#pragma unroll
      for (int j = 0; j < 8; ++j) {
        float v = af[j] + bf2f(bv[j]);
        acc[j] += v > 0.f ? v : 0.f;
      }
    }
    us8 o;
#pragma unroll
    for (int j = 0; j < 8; ++j) o[j] = f2bf(acc[j]);
    *(us8*)&xs[nl * HS + lane16 * 8] = o;
  }
}

// ---------------- kernels ----------------

// Fat kernel: block 0 = scan; blocks 1..NG = layer-1 dual GEMM (proven r10).
#define SCH ((N_PAD + 255) / 256)   // 196
__global__ __launch_bounds__(256)
void scan_gemm1(const int* __restrict__ deg,
                int* __restrict__ row_ptr,
                int* __restrict__ cursor,
                const float* __restrict__ in,
                const unsigned short* __restrict__ wpA,
                const unsigned short* __restrict__ wpB,
                const float* __restrict__ bcA,
                unsigned short* __restrict__ outA,
                unsigned short* __restrict__ outB) {
  __shared__ unsigned short xs[64 * HS];
  const int t = threadIdx.x;

  if (blockIdx.x == 0) {
    int* part = (int*)xs;
    const int lo = t * SCH;
    const int hi = min(lo + SCH, N_PAD);
    int s = 0;
    for (int i = lo; i < hi; ++i) s += deg[i];
    part[t] = s;
    __syncthreads();
    for (int off = 1; off < 256; off <<= 1) {
      int v = (t >= off) ? part[t - off] : 0;
      __syncthreads();
      part[t] += v;
      __syncthreads();
    }
    int run = (t > 0) ? part[t - 1] : 0;
    for (int i = lo; i < hi; ++i) {
      row_ptr[i] = run;
      cursor[i] = run;
      run += deg[i];
    }
    if (t == 255) row_ptr[N_PAD] = part[255];
    return;
  }

  const int r0 = (blockIdx.x - 1) * 64;
  {
    const int e = t >> 2, q = t & 3;
    const int grow = r0 + e;
    const float4* src = (const float4*)(in + (size_t)grow * DF) + q * 8;
#pragma unroll
    for (int i = 0; i < 8; ++i) {
      float4 v = { 0.f, 0.f, 0.f, 0.f };
      if (grow < N_NODES) v = src[i];
      us4 p = { f2bf(v.x), f2bf(v.y), f2bf(v.z), f2bf(v.w) };
      *(us4*)&xs[e * HS + q * 32 + i * 4] = p;
    }
  }
  __syncthreads();

  const int w = t >> 6, l = t & 63, l15 = l & 15, lg = l >> 4;
  f32x4 accA[4][2] = {};
  f32x4 accB[4][2] = {};
  const uint4v* wvA = (const uint4v*)wpA;
  const uint4v* wvB = (const uint4v*)wpB;
#pragma unroll
  for (int kc = 0; kc < 4; ++kc) {
    bf16x8 afr[4];
#pragma unroll
    for (int rt = 0; rt < 4; ++rt)
      afr[rt] = __builtin_bit_cast(bf16x8,
          *(const uint4v*)&xs[(rt * 16 + l15) * HS + kc * 32 + lg * 8]);
#pragma unroll
    for (int c = 0; c < 2; ++c) {
      bf16x8 bfrA = __builtin_bit_cast(bf16x8, wvA[((w * 2 + c) * 4 + kc) * 64 + l]);
      bf16x8 bfrB = __builtin_bit_cast(bf16x8, wvB[((w * 2 + c) * 4 + kc) * 64 + l]);
#pragma unroll
      for (int rt = 0; rt < 4; ++rt) {
        accA[rt][c] = __builtin_amdgcn_mfma_f32_16x16x32_bf16(afr[rt], bfrA, accA[rt][c], 0, 0, 0);
        accB[rt][c] = __builtin_amdgcn_mfma_f32_16x16x32_bf16(afr[rt], bfrB, accB[rt][c], 0, 0, 0);
      }
    }
  }
#pragma unroll
  for (int c = 0; c < 2; ++c) {
    const int col = w * 32 + c * 16 + l15;
    const float cA = bcA[col];
#pragma unroll
    for (int rt = 0; rt < 4; ++rt) {
#pragma unroll
      for (int r = 0; r < 4; ++r) {
        const int grow = r0 + rt * 16 + lg * 4 + r;
        outA[(size_t)grow * DF + col] = f2bf(accA[rt][c][r] + cA);
        outB[(size_t)grow * DF + col] = f2bf(accB[rt][c][r]);
      }
    }
  }
}

// Fused: Hsum1 aggregation (LDS) + combined-weight dual GEMM -> A2, B2 (proven)
__global__ __launch_bounds__(256)
void agg_dual(const unsigned short* __restrict__ A,
              const unsigned short* __restrict__ B,
              const int* __restrict__ row_ptr,
              const int2* __restrict__ sorted_se,
              const unsigned short* __restrict__ wpA,
              const unsigned short* __restrict__ wpB,
              const float* __restrict__ bcA, const float* __restrict__ bdA,
              const float* __restrict__ bdB,
              const int* __restrict__ deg,
              unsigned short* __restrict__ outA,
              unsigned short* __restrict__ outB) {
  __shared__ unsigned short xs[64 * HS];
  const int t = threadIdx.x;
  const int r0 = blockIdx.x * 64;

  agg_phase(A, B, row_ptr, sorted_se, xs, r0, t);
  __syncthreads();

  const int w = t >> 6, l = t & 63, l15 = l & 15, lg = l >> 4;
  f32x4 accA[4][2] = {};
  f32x4 accB[4][2] = {};
  const uint4v* wvA = (const uint4v*)wpA;
  const uint4v* wvB = (const uint4v*)wpB;
#pragma unroll
  for (int kc = 0; kc < 4; ++kc) {
    bf16x8 afr[4];
#pragma unroll
    for (int rt = 0; rt < 4; ++rt)
      afr[rt] = __builtin_bit_cast(bf16x8,
          *(const uint4v*)&xs[(rt * 16 + l15) * HS + kc * 32 + lg * 8]);
#pragma unroll
    for (int c = 0; c < 2; ++c) {
      bf16x8 bfrA = __builtin_bit_cast(bf16x8, wvA[((w * 2 + c) * 4 + kc) * 64 + l]);
      bf16x8 bfrB = __builtin_bit_cast(bf16x8, wvB[((w * 2 + c) * 4 + kc) * 64 + l]);
#pragma unroll
      for (int rt = 0; rt < 4; ++rt) {
        accA[rt][c] = __builtin_amdgcn_mfma_f32_16x16x32_bf16(afr[rt], bfrA, accA[rt][c], 0, 0, 0);
        accB[rt][c] = __builtin_amdgcn_mfma_f32_16x16x32_bf16(afr[rt], bfrB, accB[rt][c], 0, 0, 0);
      }
    }
  }
#pragma unroll
  for (int c = 0; c < 2; ++c) {
    const int col = w * 32 + c * 16 + l15;
    const float cA = bcA[col];
    const float dA = bdA[col];
    const float dB = bdB[col];
#pragma unroll
    for (int rt = 0; rt < 4; ++rt) {
#pragma unroll
      for (int r = 0; r < 4; ++r) {
        const int grow = r0 + rt * 16 + lg * 4 + r;
        const float dg = (float)deg[grow];
        outA[(size_t)grow * DF + col] = f2bf(accA[rt][c][r] + cA + dg * dA);
        outB[(size_t)grow * DF + col] = f2bf(accB[rt][c][r] + dg * dB);
      }
    }
  }
}

// Fused layer-2 edge kernel: h = relu(A2[dst]+B2[src]); msg = h@W21 + b2_1.
// msg tile (bf16) -> LDS; scatter msg rows (orig eid, f32x4 nt); feat2 =
// segment-sum of the biased msg tile (nt interior / atomic boundary).
__global__ __launch_bounds__(256)
void edge_fused3(const unsigned short* __restrict__ A,
                 const unsigned short* __restrict__ B,
                 const int2* __restrict__ sorted_se,
                 const int* __restrict__ sorted_dst,
                 const unsigned short* __restrict__ w2p,
                 const float* __restrict__ b2,
                 float* __restrict__ msg_out,
                 float* __restrict__ feat_out) {
  __shared__ unsigned short h_s[64 * HS];
  __shared__ int node_s[64];
  __shared__ int eid_s[64];
  const int t = threadIdx.x;
  const int e0 = blockIdx.x * 64;

  // ---- stage h (proven)
  {
    const int e = t >> 2, q = t & 3;
    const int pos = e0 + e;
    const int2 se = sorted_se[pos];
    const int di = sorted_dst[pos];
    if (q == 0) { node_s[e] = di; eid_s[e] = se.y; }
    const us8* ap = (const us8*)(A + (size_t)di * DF + q * 32);
    const us8* bp = (const us8*)(B + (size_t)se.x * DF + q * 32);
    us8 av[4], bv[4];
#pragma unroll
    for (int i = 0; i < 4; ++i) { av[i] = ap[i]; bv[i] = bp[i]; }
#pragma unroll
    for (int i = 0; i < 4; ++i) {
      us8 h;
#pragma unroll
      for (int j = 0; j < 8; ++j) {
        float v = bf2f(av[i][j]) + bf2f(bv[i][j]);
        v = v > 0.f ? v : 0.f;
        h[j] = f2bf(v);
      }
      *(us8*)&h_s[e * HS + q * 32 + i * 8] = h;
    }
  }
  __syncthreads();

  const int w = t >> 6, l = t & 63, l15 = l & 15, lg = l >> 4;

  // ---- GEMM: msg = h @ W21 (proven)
  f32x4 acc[4][2] = {};
  const uint4v* wv = (const uint4v*)w2p;
#pragma unroll
  for (int kc = 0; kc < 4; ++kc) {
    bf16x8 afr[4];
#pragma unroll
    for (int rt = 0; rt < 4; ++rt)
      afr[rt] = __builtin_bit_cast(bf16x8,
          *(const uint4v*)&h_s[(rt * 16 + l15) * HS + kc * 32 + lg * 8]);
#pragma unroll
    for (int c = 0; c < 2; ++c) {
      bf16x8 bfr = __builtin_bit_cast(bf16x8, wv[((w * 2 + c) * 4 + kc) * 64 + l]);
#pragma unroll
      for (int rt = 0; rt < 4; ++rt)
        acc[rt][c] = __builtin_amdgcn_mfma_f32_16x16x32_bf16(afr[rt], bfr, acc[rt][c], 0, 0, 0);
    }
  }
  __syncthreads();   // all GEMM reads of h_s done before overwrite

  // ---- overwrite h_s with biased msg tile (bf16)
#pragma unroll
  for (int c = 0; c < 2; ++c) {
    const int col = w * 32 + c * 16 + l15;
    const float bv = b2[col];
#pragma unroll
    for (int rt = 0; rt < 4; ++rt) {
#pragma unroll
      for (int r = 0; r < 4; ++r)
        h_s[(rt * 16 + lg * 4 + r) * HS + col] = f2bf(acc[rt][c][r] + bv);
    }
  }
  __syncthreads();

  // ---- scatter msg rows (orig eid, row-coalesced f32x4 nt)
  {
    const int off = (t & 31) * 4;
    const int rbase = t >> 5;
#pragma unroll
    for (int p = 0; p < 8; ++p) {
      const int row = p * 8 + rbase;
      us4 hv = *(const us4*)&h_s[row * HS + off];
      f32x4 o = { bf2f(hv[0]), bf2f(hv[1]), bf2f(hv[2]), bf2f(hv[3]) };
      __builtin_nontemporal_store(o, (f32x4*)(msg_out + (size_t)eid_s[row] * DF + off));
    }
  }

  // ---- feat2: serial segmented column scan over the msg tile (proven scheme)
  if (t < 128) {
    const int col = t;
    const int prev = (e0 > 0) ? sorted_dst[e0 - 1] : -1;
    const int next = (e0 + 64 < N_EDGES) ? sorted_dst[e0 + 64] : -1;
    int run_n = node_s[0];
    int run_a = 0;
    float racc = 0.f;
    for (int r = 0; r < 64; ++r) {
      const int n = node_s[r];
      if (n != run_n) {
        float* p = &feat_out[(size_t)run_n * DF + col];
        if (run_a == 0 && prev == run_n) unsafeAtomicAdd(p, racc);
        else __builtin_nontemporal_store(racc, p);
        run_n = n; run_a = r; racc = 0.f;
      }
      racc += bf2f(h_s[r * HS + col]);
    }
    float* p = &feat_out[(size_t)run_n * DF + col];
    if ((run_a == 0 && prev == run_n) || next == run_n) unsafeAtomicAdd(p, racc);
    else __builtin_nontemporal_store(racc, p);
  }
}

extern "C" void kernel_launch(void* const* d_in, const int* in_sizes, int n_in,
                              void* d_out, int out_size, void* d_ws, size_t ws_size,
                              hipStream_t stream) {
  const float* x    = (const float*)d_in[0];
  const int*   eidx = (const int*)d_in[1];
  const float* W1_0 = (const float*)d_in[2];
  const float* b1_0 = (const float*)d_in[3];
  const float* W2_0 = (const float*)d_in[4];
  const float* b2_0 = (const float*)d_in[5];
  const float* W1_1 = (const float*)d_in[6];
  const float* b1_1 = (const float*)d_in[7];
  const float* W2_1 = (const float*)d_in[8];
  const float* b2_1 = (const float*)d_in[9];

  const int* src = eidx;
  const int* dst = eidx + N_EDGES;

  float* feat2 = (float*)d_out;
  float* msg2  = feat2 + (size_t)N_NODES * DF;

  // ---- workspace layout (~62 MB; 8-B arrays placed first for alignment) ----
  char* ws = (char*)d_ws;
  const size_t BF_ROWS = (size_t)N_PAD * DF;
  unsigned short* A1 = (unsigned short*)ws;  ws += BF_ROWS * 2;   // 12.8 MB
  unsigned short* B1 = (unsigned short*)ws;  ws += BF_ROWS * 2;   // 12.8 MB
  unsigned short* A2 = (unsigned short*)ws;  ws += BF_ROWS * 2;   // 12.8 MB
  unsigned short* B2 = (unsigned short*)ws;  ws += BF_ROWS * 2;   // 12.8 MB
  int2* sorted_se = (int2*)ws; ws += (size_t)N_EDGES * 8;         // 6.4 MB (8-B aligned)
  int* sorted_dst = (int*)ws;  ws += (size_t)N_EDGES * 4;         // 3.2 MB
  int* deg        = (int*)ws;  ws += (size_t)N_PAD * 4;
  int* row_ptr    = (int*)ws;  ws += (size_t)(N_PAD + 1) * 4;
  int* cursor     = (int*)ws;  ws += (size_t)N_PAD * 4;
  float* vA     = (float*)ws;  ws += 128 * 4;
  float* vB     = (float*)ws;  ws += 128 * 4;
  unsigned short* wa1p  = (unsigned short*)ws;  ws += 16384 * 2;
  unsigned short* wb1p  = (unsigned short*)ws;  ws += 16384 * 2;
  unsigned short* w21p  = (unsigned short*)ws;  ws += 16384 * 2;
  unsigned short* w20Ap = (unsigned short*)ws;  ws += 16384 * 2;
  unsigned short* w20Bp = (unsigned short*)ws;  ws += 16384 * 2;

  hipMemsetAsync(deg, 0, (size_t)N_PAD * 4, stream);
  // feat2 zero-init: boundary segments atomicAdd onto it; deg-0 nodes stay 0.
  hipMemsetAsync(feat2, 0, (size_t)N_NODES * DF * 4, stream);

  // Fused weight prep (wcomb direct-packed + 3 packs) + deg histogram.
  wprep_deg<<<153 + DEG_BLOCKS, 256, 0, stream>>>(
      W2_0, W1_1, b2_0, W1_0, W2_1,
      w20Ap, w20Bp, vA, vB, wa1p, wb1p, w21p, dst, deg);

  // Fat: scan (block 0) + layer-1 dual GEMM (blocks 1..NG).
  scan_gemm1<<<1 + NG, 256, 0, stream>>>(deg, row_ptr, cursor,
                                         x, wa1p, wb1p, b1_0, A1, B1);

  sort_kernel<<<DEG_BLOCKS, 256, 0, stream>>>(src, dst, cursor,
                                              sorted_se, sorted_dst);

  // Fused aggregate(Hsum1) + combined-weight dual GEMM -> A2, B2
  agg_dual<<<NG, 256, 0, stream>>>(A1, B1, row_ptr, sorted_se,
                                   w20Ap, w20Bp, b1_1, vA, vB, deg, A2, B2);

  // Fused: msg2 (f32x4 nt scatter) + feat2 (segment-sum of biased msg tile)
  edge_fused3<<<N_EDGES / 64, 256, 0, stream>>>(A2, B2, sorted_se, sorted_dst,
                                                w21p, b2_1, msg2, feat2);
}

// Round 13
// 418.472 us; speedup vs baseline: 1.2902x; 1.0087x over previous
//
#include <hip/hip_runtime.h>
#include <hip/hip_bf16.h>

#define N_NODES 50000
#define N_PAD   50048      // 64-row multiple for guard-free GEMM tiles
#define N_EDGES 800000
#define DF 128
#define NG (N_PAD / 64)    // 782 node-GEMM blocks
#define DEG_BLOCKS (N_EDGES / 256)  // 3125

// LDS row stride (ushorts): 128 bf16 + 8 pad (272 B = 17*16 B)
#define HS 136

typedef __bf16 bf16x8 __attribute__((ext_vector_type(8)));
typedef float f32x4 __attribute__((ext_vector_type(4)));
typedef unsigned int uint4v __attribute__((ext_vector_type(4)));
typedef unsigned short us4 __attribute__((ext_vector_type(4)));
typedef unsigned short us8 __attribute__((ext_vector_type(8)));

__device__ __forceinline__ unsigned short f2bf(float f) {
  unsigned u = __builtin_bit_cast(unsigned, f);
  u += 0x7FFFu + ((u >> 16) & 1u);   // RNE
  return (unsigned short)(u >> 16);
}
__device__ __forceinline__ float bf2f(unsigned short u) {
  return __builtin_bit_cast(float, ((unsigned)u) << 16);
}

// Packed-fragment offset for element (k,col) of a [128][128] matrix.
__device__ __forceinline__ int pack_off(int k, int c) {
  return ((((c >> 4) * 4 + (k >> 5)) * 64) + ((k >> 3) & 3) * 16 + (c & 15)) * 8
         + (k & 7);
}

// ---------------- fused weight prep + deg histogram (proven r10) ----------------
__global__ __launch_bounds__(256)
void wprep_deg(const float* __restrict__ W2_0,
               const float* __restrict__ W1_1,
               const float* __restrict__ b2_0,
               const float* __restrict__ W1_0,
               const float* __restrict__ W2_1,
               unsigned short* __restrict__ w20Ap,
               unsigned short* __restrict__ w20Bp,
               float* __restrict__ vA,
               float* __restrict__ vB,
               unsigned short* __restrict__ wa1p,
               unsigned short* __restrict__ wb1p,
               unsigned short* __restrict__ w21p,
               const int* __restrict__ dst,
               int* __restrict__ deg) {
  const int b = blockIdx.x;
  const int t = threadIdx.x;

  if (b < 129) {                      // wcomb, direct-packed
    const int c = t & 127;
    const bool isB = t >= 128;
    float acc = 0.f;
    if (b < 128) {
      const float* wrow = W2_0 + (size_t)b * DF;
      for (int k = 0; k < 128; ++k) {
        float bot = W1_1[(size_t)(128 + k) * DF + c];
        float w = isB ? bot : (W1_1[(size_t)k * DF + c] - bot);
        acc += wrow[k] * w;
      }
      unsigned short* out = isB ? w20Bp : w20Ap;
      out[pack_off(b, c)] = f2bf(acc);
    } else {
      for (int k = 0; k < 128; ++k) {
        float bot = W1_1[(size_t)(128 + k) * DF + c];
        float w = isB ? bot : (W1_1[(size_t)k * DF + c] - bot);
        acc += b2_0[k] * w;
      }
      if (isB) vB[c] = acc;
      else     vA[c] = acc;
    }
    return;
  }

  if (b < 153) {                      // pack wa1p / wb1p / w21p
    const int mat = (b - 129) >> 3;
    const int idx = ((b - 129) & 7) * 256 + t;   // < 2048
    const int l = idx & 63;
    const int blk = idx >> 6;
    const int ct = blk >> 2;
    const int kc = blk & 3;
    const int col = ct * 16 + (l & 15);
    const int k0 = kc * 32 + (l >> 4) * 8;
    const float* W;
    const float* Wsub = nullptr;
    unsigned short* out;
    if (mat == 0)      { W = W1_0;            Wsub = W1_0 + 128 * DF; out = wa1p; }
    else if (mat == 1) { W = W1_0 + 128 * DF;                         out = wb1p; }
    else               { W = W2_1;                                    out = w21p; }
    unsigned short tmp[8];
#pragma unroll
    for (int j = 0; j < 8; ++j) {
      float v = W[(size_t)(k0 + j) * DF + col];
      if (Wsub) v -= Wsub[(size_t)(k0 + j) * DF + col];
      tmp[j] = f2bf(v);
    }
    us4 lo = { tmp[0], tmp[1], tmp[2], tmp[3] };
    us4 hi = { tmp[4], tmp[5], tmp[6], tmp[7] };
    us4* o = (us4*)(out + (size_t)idx * 8);
    o[0] = lo;
    o[1] = hi;
    return;
  }

  // deg histogram
  const int e = (b - 153) * 256 + t;
  if (e < N_EDGES) atomicAdd(&deg[dst[e]], 1);
}

// ---------------- CSR sort: packed (src,eid) + dst (proven r12) ----------------
__global__ void sort_kernel(const int* __restrict__ src,
                            const int* __restrict__ dst,
                            int* __restrict__ cursor,
                            int2* __restrict__ sorted_se,
                            int* __restrict__ sorted_dst) {
  const int e = blockIdx.x * 256 + threadIdx.x;
  const int d = dst[e];
  const int pos = atomicAdd(&cursor[d], 1);
  sorted_se[pos] = make_int2(src[e], e);
  sorted_dst[pos] = d;
}

// ---------------- shared device pieces (proven r12) ----------------
__device__ __forceinline__ void agg_phase(const unsigned short* __restrict__ A,
                                          const unsigned short* __restrict__ B,
                                          const int* __restrict__ row_ptr,
                                          const int2* __restrict__ sorted_se,
                                          unsigned short* xs, int r0, int t) {
  const int w = t >> 6, l = t & 63;
  const int lane16 = l & 15;
  const int g = l >> 4;
#pragma unroll
  for (int i = 0; i < 4; ++i) {
    const int nl = w * 16 + i * 4 + g;       // 0..63
    const int n = r0 + nl;
    const int beg = row_ptr[n];
    const int end = row_ptr[n + 1];
    us8 av = *(const us8*)(A + (size_t)n * DF + lane16 * 8);
    float af[8];
#pragma unroll
    for (int j = 0; j < 8; ++j) af[j] = bf2f(av[j]);
    float acc[8] = {};
    int k = beg;
    for (; k + 8 <= end; k += 8) {
      us8 bv[8];
#pragma unroll
      for (int u = 0; u < 8; ++u) {
        const int s = sorted_se[k + u].x;
        bv[u] = *(const us8*)(B + (size_t)s * DF + lane16 * 8);
      }
#pragma unroll
      for (int j = 0; j < 8; ++j) {
#pragma unroll
        for (int u = 0; u < 8; ++u) {
          float v = af[j] + bf2f(bv[u][j]);
          acc[j] += v > 0.f ? v : 0.f;
        }
      }
    }
    for (; k < end; ++k) {
      const int s = sorted_se[k].x;
      us8 bv = *(const us8*)(B + (size_t)s * DF + lane16 * 8);
#pragma unroll
      for (int j = 0; j < 8; ++j) {
        float v = af[j] + bf2f(bv[j]);
        acc[j] += v > 0.f ? v : 0.f;
      }
    }
    us8 o;
#pragma unroll
    for (int j = 0; j < 8; ++j) o[j] = f2bf(acc[j]);
    *(us8*)&xs[nl * HS + lane16 * 8] = o;
  }
}

// ---------------- kernels ----------------

// Fat kernel: block 0 = scan; blocks 1..NG = layer-1 dual GEMM (proven r10).
#define SCH ((N_PAD + 255) / 256)   // 196
__global__ __launch_bounds__(256)
void scan_gemm1(const int* __restrict__ deg,
                int* __restrict__ row_ptr,
                int* __restrict__ cursor,
                const float* __restrict__ in,
                const unsigned short* __restrict__ wpA,
                const unsigned short* __restrict__ wpB,
                const float* __restrict__ bcA,
                unsigned short* __restrict__ outA,
                unsigned short* __restrict__ outB) {
  __shared__ unsigned short xs[64 * HS];
  const int t = threadIdx.x;

  if (blockIdx.x == 0) {
    int* part = (int*)xs;
    const int lo = t * SCH;
    const int hi = min(lo + SCH, N_PAD);
    int s = 0;
    for (int i = lo; i < hi; ++i) s += deg[i];
    part[t] = s;
    __syncthreads();
    for (int off = 1; off < 256; off <<= 1) {
      int v = (t >= off) ? part[t - off] : 0;
      __syncthreads();
      part[t] += v;
      __syncthreads();
    }
    int run = (t > 0) ? part[t - 1] : 0;
    for (int i = lo; i < hi; ++i) {
      row_ptr[i] = run;
      cursor[i] = run;
      run += deg[i];
    }
    if (t == 255) row_ptr[N_PAD] = part[255];
    return;
  }

  const int r0 = (blockIdx.x - 1) * 64;
  {
    const int e = t >> 2, q = t & 3;
    const int grow = r0 + e;
    const float4* src = (const float4*)(in + (size_t)grow * DF) + q * 8;
#pragma unroll
    for (int i = 0; i < 8; ++i) {
      float4 v = { 0.f, 0.f, 0.f, 0.f };
      if (grow < N_NODES) v = src[i];
      us4 p = { f2bf(v.x), f2bf(v.y), f2bf(v.z), f2bf(v.w) };
      *(us4*)&xs[e * HS + q * 32 + i * 4] = p;
    }
  }
  __syncthreads();

  const int w = t >> 6, l = t & 63, l15 = l & 15, lg = l >> 4;
  f32x4 accA[4][2] = {};
  f32x4 accB[4][2] = {};
  const uint4v* wvA = (const uint4v*)wpA;
  const uint4v* wvB = (const uint4v*)wpB;
#pragma unroll
  for (int kc = 0; kc < 4; ++kc) {
    bf16x8 afr[4];
#pragma unroll
    for (int rt = 0; rt < 4; ++rt)
      afr[rt] = __builtin_bit_cast(bf16x8,
          *(const uint4v*)&xs[(rt * 16 + l15) * HS + kc * 32 + lg * 8]);
#pragma unroll
    for (int c = 0; c < 2; ++c) {
      bf16x8 bfrA = __builtin_bit_cast(bf16x8, wvA[((w * 2 + c) * 4 + kc) * 64 + l]);
      bf16x8 bfrB = __builtin_bit_cast(bf16x8, wvB[((w * 2 + c) * 4 + kc) * 64 + l]);
#pragma unroll
      for (int rt = 0; rt < 4; ++rt) {
        accA[rt][c] = __builtin_amdgcn_mfma_f32_16x16x32_bf16(afr[rt], bfrA, accA[rt][c], 0, 0, 0);
        accB[rt][c] = __builtin_amdgcn_mfma_f32_16x16x32_bf16(afr[rt], bfrB, accB[rt][c], 0, 0, 0);
      }
    }
  }
#pragma unroll
  for (int c = 0; c < 2; ++c) {
    const int col = w * 32 + c * 16 + l15;
    const float cA = bcA[col];
#pragma unroll
    for (int rt = 0; rt < 4; ++rt) {
#pragma unroll
      for (int r = 0; r < 4; ++r) {
        const int grow = r0 + rt * 16 + lg * 4 + r;
        outA[(size_t)grow * DF + col] = f2bf(accA[rt][c][r] + cA);
        outB[(size_t)grow * DF + col] = f2bf(accB[rt][c][r]);
      }
    }
  }
}

// Fused: Hsum1 aggregation (LDS) + combined-weight dual GEMM -> A2, B2 (proven)
__global__ __launch_bounds__(256)
void agg_dual(const unsigned short* __restrict__ A,
              const unsigned short* __restrict__ B,
              const int* __restrict__ row_ptr,
              const int2* __restrict__ sorted_se,
              const unsigned short* __restrict__ wpA,
              const unsigned short* __restrict__ wpB,
              const float* __restrict__ bcA, const float* __restrict__ bdA,
              const float* __restrict__ bdB,
              const int* __restrict__ deg,
              unsigned short* __restrict__ outA,
              unsigned short* __restrict__ outB) {
  __shared__ unsigned short xs[64 * HS];
  const int t = threadIdx.x;
  const int r0 = blockIdx.x * 64;

  agg_phase(A, B, row_ptr, sorted_se, xs, r0, t);
  __syncthreads();

  const int w = t >> 6, l = t & 63, l15 = l & 15, lg = l >> 4;
  f32x4 accA[4][2] = {};
  f32x4 accB[4][2] = {};
  const uint4v* wvA = (const uint4v*)wpA;
  const uint4v* wvB = (const uint4v*)wpB;
#pragma unroll
  for (int kc = 0; kc < 4; ++kc) {
    bf16x8 afr[4];
#pragma unroll
    for (int rt = 0; rt < 4; ++rt)
      afr[rt] = __builtin_bit_cast(bf16x8,
          *(const uint4v*)&xs[(rt * 16 + l15) * HS + kc * 32 + lg * 8]);
#pragma unroll
    for (int c = 0; c < 2; ++c) {
      bf16x8 bfrA = __builtin_bit_cast(bf16x8, wvA[((w * 2 + c) * 4 + kc) * 64 + l]);
      bf16x8 bfrB = __builtin_bit_cast(bf16x8, wvB[((w * 2 + c) * 4 + kc) * 64 + l]);
#pragma unroll
      for (int rt = 0; rt < 4; ++rt) {
        accA[rt][c] = __builtin_amdgcn_mfma_f32_16x16x32_bf16(afr[rt], bfrA, accA[rt][c], 0, 0, 0);
        accB[rt][c] = __builtin_amdgcn_mfma_f32_16x16x32_bf16(afr[rt], bfrB, accB[rt][c], 0, 0, 0);
      }
    }
  }
#pragma unroll
  for (int c = 0; c < 2; ++c) {
    const int col = w * 32 + c * 16 + l15;
    const float cA = bcA[col];
    const float dA = bdA[col];
    const float dB = bdB[col];
#pragma unroll
    for (int rt = 0; rt < 4; ++rt) {
#pragma unroll
      for (int r = 0; r < 4; ++r) {
        const int grow = r0 + rt * 16 + lg * 4 + r;
        const float dg = (float)deg[grow];
        outA[(size_t)grow * DF + col] = f2bf(accA[rt][c][r] + cA + dg * dA);
        outB[(size_t)grow * DF + col] = f2bf(accB[rt][c][r] + dg * dB);
      }
    }
  }
}

// Fused layer-2 edge kernel: h = relu(A2[dst]+B2[src]); msg = h@W21 + b2_1;
// msg tile (bf16) -> LDS; f32x4 nt scatter to msg[orig eid]; feat2 = segment
// sums of the biased msg tile via indicator-matrix MFMA (FIXED segmentation:
// segid includes own flag — r7's off-by-one left seg_node_s[nseg-1]
// uninitialized -> OOB; corrected here). Boundary segments atomic.
__global__ __launch_bounds__(256)
void edge_fused4(const unsigned short* __restrict__ A,
                 const unsigned short* __restrict__ B,
                 const int2* __restrict__ sorted_se,
                 const int* __restrict__ sorted_dst,
                 const unsigned short* __restrict__ w2p,
                 const float* __restrict__ b2,
                 float* __restrict__ msg_out,
                 float* __restrict__ feat_out) {
  __shared__ unsigned short h_s[64 * HS];
  __shared__ int node_s[64];
  __shared__ int eid_s[64];
  __shared__ unsigned char segid_s[64];
  __shared__ int seg_node_s[64];
  __shared__ int nseg_s;
  const int t = threadIdx.x;
  const int e0 = blockIdx.x * 64;

  // ---- stage h (proven)
  {
    const int e = t >> 2, q = t & 3;
    const int pos = e0 + e;
    const int2 se = sorted_se[pos];
    const int di = sorted_dst[pos];
    if (q == 0) { node_s[e] = di; eid_s[e] = se.y; }
    const us8* ap = (const us8*)(A + (size_t)di * DF + q * 32);
    const us8* bp = (const us8*)(B + (size_t)se.x * DF + q * 32);
    us8 av[4], bv[4];
#pragma unroll
    for (int i = 0; i < 4; ++i) { av[i] = ap[i]; bv[i] = bp[i]; }
#pragma unroll
    for (int i = 0; i < 4; ++i) {
      us8 h;
#pragma unroll
      for (int j = 0; j < 8; ++j) {
        float v = bf2f(av[i][j]) + bf2f(bv[i][j]);
        v = v > 0.f ? v : 0.f;
        h[j] = f2bf(v);
      }
      *(us8*)&h_s[e * HS + q * 32 + i * 8] = h;
    }
  }
  __syncthreads();

  // ---- segmentation (wave 0; segid INCLUDES own flag — the r7 fix)
  if (t < 64) {
    const int flag = (t > 0 && node_s[t] != node_s[t - 1]) ? 1 : 0;
    const unsigned long long m = __ballot(flag);
    const int sid = (int)__popcll(m & ((1ull << t) - 1ull)) + flag;
    segid_s[t] = (unsigned char)sid;
    if (flag || t == 0) seg_node_s[sid] = node_s[t];
    if (t == 63) nseg_s = sid + 1;
  }

  const int w = t >> 6, l = t & 63, l15 = l & 15, lg = l >> 4;

  // ---- GEMM: msg = h @ W21 (proven)
  f32x4 acc[4][2] = {};
  const uint4v* wv = (const uint4v*)w2p;
#pragma unroll
  for (int kc = 0; kc < 4; ++kc) {
    bf16x8 afr[4];
#pragma unroll
    for (int rt = 0; rt < 4; ++rt)
      afr[rt] = __builtin_bit_cast(bf16x8,
          *(const uint4v*)&h_s[(rt * 16 + l15) * HS + kc * 32 + lg * 8]);
#pragma unroll
    for (int c = 0; c < 2; ++c) {
      bf16x8 bfr = __builtin_bit_cast(bf16x8, wv[((w * 2 + c) * 4 + kc) * 64 + l]);
#pragma unroll
      for (int rt = 0; rt < 4; ++rt)
        acc[rt][c] = __builtin_amdgcn_mfma_f32_16x16x32_bf16(afr[rt], bfr, acc[rt][c], 0, 0, 0);
    }
  }
  __syncthreads();   // GEMM reads of h_s done; segmentation visible to all

  // ---- overwrite h_s with biased msg tile (bf16)
#pragma unroll
  for (int c = 0; c < 2; ++c) {
    const int col = w * 32 + c * 16 + l15;
    const float bv = b2[col];
#pragma unroll
    for (int rt = 0; rt < 4; ++rt) {
#pragma unroll
      for (int r = 0; r < 4; ++r)
        h_s[(rt * 16 + lg * 4 + r) * HS + col] = f2bf(acc[rt][c][r] + bv);
    }
  }
  __syncthreads();

  // ---- scatter msg rows (orig eid, row-coalesced f32x4 nt)
  {
    const int off = (t & 31) * 4;
    const int rbase = t >> 5;
#pragma unroll
    for (int p = 0; p < 8; ++p) {
      const int row = p * 8 + rbase;
      us4 hv = *(const us4*)&h_s[row * HS + off];
      f32x4 o = { bf2f(hv[0]), bf2f(hv[1]), bf2f(hv[2]), bf2f(hv[3]) };
      __builtin_nontemporal_store(o, (f32x4*)(msg_out + (size_t)eid_s[row] * DF + off));
    }
  }

  // ---- feat2: segment sums S = I(32seg x 64edge) @ msg(64 x 128) via MFMA
  const int nseg = nseg_s;
  if (nseg <= 32) {
    f32x4 sacc[2][2] = {};
#pragma unroll
    for (int kc = 0; kc < 2; ++kc) {
      bf16x8 ifr[2];
#pragma unroll
      for (int st = 0; st < 2; ++st) {
        const int srow = st * 16 + l15;
#pragma unroll
        for (int j = 0; j < 8; ++j)
          ifr[st][j] = (segid_s[kc * 32 + lg * 8 + j] == srow) ? (__bf16)1.0f
                                                               : (__bf16)0.0f;
      }
#pragma unroll
      for (int c = 0; c < 2; ++c) {
        const int col = w * 32 + c * 16 + l15;
        bf16x8 hfr;
#pragma unroll
        for (int j = 0; j < 8; ++j)
          hfr[j] = *(const __bf16*)&h_s[(kc * 32 + lg * 8 + j) * HS + col];
#pragma unroll
        for (int st = 0; st < 2; ++st)
          sacc[st][c] = __builtin_amdgcn_mfma_f32_16x16x32_bf16(ifr[st], hfr, sacc[st][c], 0, 0, 0);
      }
    }
    const bool prevSame = (blockIdx.x > 0) && (sorted_dst[e0 - 1] == node_s[0]);
    const bool nextSame = (e0 + 64 < N_EDGES) && (sorted_dst[e0 + 64] == node_s[63]);
#pragma unroll
    for (int st = 0; st < 2; ++st) {
#pragma unroll
      for (int c = 0; c < 2; ++c) {
        const int col = w * 32 + c * 16 + l15;
#pragma unroll
        for (int r = 0; r < 4; ++r) {
          const int s = st * 16 + lg * 4 + r;
          if (s < nseg) {
            float* p = &feat_out[(size_t)seg_node_s[s] * DF + col];
            const float v = sacc[st][c][r];
            const bool bd = (s == 0 && prevSame) || (s == nseg - 1 && nextSame);
            if (bd) unsafeAtomicAdd(p, v);
            else __builtin_nontemporal_store(v, p);
          }
        }
      }
    }
  } else {
    // all-atomic scalar fallback (correctness only; nseg>32 ~ impossible)
    const int col = t & 127;
    const int rbeg = (t >> 7) * 32, rend = rbeg + 32;
    float racc = 0.f;
    int run_n = node_s[rbeg];
    for (int r = rbeg; r < rend; ++r) {
      const int n = node_s[r];
      if (n != run_n) {
        unsafeAtomicAdd(&feat_out[(size_t)run_n * DF + col], racc);
        run_n = n; racc = 0.f;
      }
      racc += bf2f(h_s[r * HS + col]);
    }
    unsafeAtomicAdd(&feat_out[(size_t)run_n * DF + col], racc);
  }
}

extern "C" void kernel_launch(void* const* d_in, const int* in_sizes, int n_in,
                              void* d_out, int out_size, void* d_ws, size_t ws_size,
                              hipStream_t stream) {
  const float* x    = (const float*)d_in[0];
  const int*   eidx = (const int*)d_in[1];
  const float* W1_0 = (const float*)d_in[2];
  const float* b1_0 = (const float*)d_in[3];
  const float* W2_0 = (const float*)d_in[4];
  const float* b2_0 = (const float*)d_in[5];
  const float* W1_1 = (const float*)d_in[6];
  const float* b1_1 = (const float*)d_in[7];
  const float* W2_1 = (const float*)d_in[8];
  const float* b2_1 = (const float*)d_in[9];

  const int* src = eidx;
  const int* dst = eidx + N_EDGES;

  float* feat2 = (float*)d_out;
  float* msg2  = feat2 + (size_t)N_NODES * DF;

  // ---- workspace layout (~62 MB; 8-B arrays first for alignment) ----
  char* ws = (char*)d_ws;
  const size_t BF_ROWS = (size_t)N_PAD * DF;
  unsigned short* A1 = (unsigned short*)ws;  ws += BF_ROWS * 2;   // 12.8 MB
  unsigned short* B1 = (unsigned short*)ws;  ws += BF_ROWS * 2;   // 12.8 MB
  unsigned short* A2 = (unsigned short*)ws;  ws += BF_ROWS * 2;   // 12.8 MB
  unsigned short* B2 = (unsigned short*)ws;  ws += BF_ROWS * 2;   // 12.8 MB
  int2* sorted_se = (int2*)ws; ws += (size_t)N_EDGES * 8;         // 6.4 MB
  int* sorted_dst = (int*)ws;  ws += (size_t)N_EDGES * 4;         // 3.2 MB
  int* deg        = (int*)ws;  ws += (size_t)N_PAD * 4;
  int* row_ptr    = (int*)ws;  ws += (size_t)(N_PAD + 1) * 4;
  int* cursor     = (int*)ws;  ws += (size_t)N_PAD * 4;
  float* vA     = (float*)ws;  ws += 128 * 4;
  float* vB     = (float*)ws;  ws += 128 * 4;
  unsigned short* wa1p  = (unsigned short*)ws;  ws += 16384 * 2;
  unsigned short* wb1p  = (unsigned short*)ws;  ws += 16384 * 2;
  unsigned short* w21p  = (unsigned short*)ws;  ws += 16384 * 2;
  unsigned short* w20Ap = (unsigned short*)ws;  ws += 16384 * 2;
  unsigned short* w20Bp = (unsigned short*)ws;  ws += 16384 * 2;

  hipMemsetAsync(deg, 0, (size_t)N_PAD * 4, stream);
  // feat2 zero-init: boundary segments atomicAdd onto it; deg-0 nodes stay 0.
  hipMemsetAsync(feat2, 0, (size_t)N_NODES * DF * 4, stream);

  // Fused weight prep (wcomb direct-packed + 3 packs) + deg histogram.
  wprep_deg<<<153 + DEG_BLOCKS, 256, 0, stream>>>(
      W2_0, W1_1, b2_0, W1_0, W2_1,
      w20Ap, w20Bp, vA, vB, wa1p, wb1p, w21p, dst, deg);

  // Fat: scan (block 0) + layer-1 dual GEMM (blocks 1..NG).
  scan_gemm1<<<1 + NG, 256, 0, stream>>>(deg, row_ptr, cursor,
                                         x, wa1p, wb1p, b1_0, A1, B1);

  sort_kernel<<<DEG_BLOCKS, 256, 0, stream>>>(src, dst, cursor,
                                              sorted_se, sorted_dst);

  // Fused aggregate(Hsum1) + combined-weight dual GEMM -> A2, B2
  agg_dual<<<NG, 256, 0, stream>>>(A1, B1, row_ptr, sorted_se,
                                   w20Ap, w20Bp, b1_1, vA, vB, deg, A2, B2);

  // Fused: msg2 (f32x4 nt scatter) + feat2 (indicator-MFMA segment sums)
  edge_fused4<<<N_EDGES / 64, 256, 0, stream>>>(A2, B2, sorted_se, sorted_dst,
                                                w21p, b2_1, msg2, feat2);
}